// Round 5
// baseline (11387.255 us; speedup 1.0000x reference)
//
#include <hip/hip_runtime.h>
#include <hip/hip_bf16.h>

typedef __hip_bfloat16 bf16;
typedef __attribute__((ext_vector_type(4))) float f32x4;
typedef __attribute__((ext_vector_type(8))) short bf16x8;
typedef unsigned long long u64;
typedef unsigned short u16;
typedef unsigned u32;

#define T_STEPS 512
#define BATCH   32
#define DIM     1024
#define HID     1024
#define GATES   4096
#define NBLK    128   // 2 domains (batch halves) x 64 blocks

static __device__ __forceinline__ float sigmf(float x) {
    return 1.0f / (1.0f + __expf(-x));
}
// overflow-safe tanh via exp: +/-inf exp -> correct +/-1, no NaN
static __device__ __forceinline__ float tanhfast(float x) {
    return 1.0f - 2.0f / (__expf(2.0f * x) + 1.0f);
}

// coherent (LLC-level) access helpers: relaxed agent atomics emit sc-qualified
// device-scope ops -- NO cache-wide fences; L1/L2 stay warm for Wh/gx.
static __device__ __forceinline__ u64 ldc_u64(const u64* p) {
    return __hip_atomic_load((u64*)p, __ATOMIC_RELAXED, __HIP_MEMORY_SCOPE_AGENT);
}
static __device__ __forceinline__ void stc_u64(u64* p, u64 v) {
    __hip_atomic_store(p, v, __ATOMIC_RELAXED, __HIP_MEMORY_SCOPE_AGENT);
}
static __device__ __forceinline__ void stc_u32(u32* p, u32 v) {
    __hip_atomic_store(p, v, __ATOMIC_RELAXED, __HIP_MEMORY_SCOPE_AGENT);
}

// one wave polls all 64 per-block tags; release = coherent dword store after
// the producing wave's vmcnt(0) drain (stores LLC-acked). No leader, no RMW.
static __device__ __forceinline__ void wait_tags(const u32* tags, u32 need) {
    const int l = threadIdx.x & 63;
    u32 v = __hip_atomic_load(tags + l, __ATOMIC_RELAXED, __HIP_MEMORY_SCOPE_AGENT);
    while (!__all((int)(v >= need))) {
        __builtin_amdgcn_s_sleep(1);
        v = __hip_atomic_load(tags + l, __ATOMIC_RELAXED, __HIP_MEMORY_SCOPE_AGENT);
    }
}

// ---------------------------------------------------------------- prep ----
__global__ void prep_kernel(const float* __restrict__ input,
                            const float* __restrict__ Wx,
                            const float* __restrict__ Wh,
                            const float* __restrict__ h0,
                            bf16* __restrict__ input_b,
                            bf16* __restrict__ Wx_b,
                            bf16* __restrict__ Wh_b,
                            bf16* __restrict__ h_b,
                            u32* __restrict__ ex) {
    const size_t NIN = (size_t)T_STEPS * BATCH * DIM;
    const size_t NW  = (size_t)GATES * DIM;
    const size_t NH  = (size_t)BATCH * HID;
    const size_t stride = (size_t)gridDim.x * blockDim.x;
    const size_t t0 = (size_t)blockIdx.x * blockDim.x + threadIdx.x;
    for (size_t i = t0; i < NIN; i += stride) input_b[i] = __float2bfloat16(input[i]);
    for (size_t i = t0; i < NW;  i += stride) Wx_b[i]    = __float2bfloat16(Wx[i]);
    for (size_t i = t0; i < NW;  i += stride) Wh_b[i]    = __float2bfloat16(Wh[i]);
    for (size_t i = t0; i < NH;  i += stride) h_b[i]     = __float2bfloat16(h0[i]);
    if (t0 < 16384) ex[t0] = 0u;   // 2 domains x 32KB exchange state
}

// ------------------------------------------------- big GEMM: gates_x -----
__global__ __launch_bounds__(256) void gemm_input(const bf16* __restrict__ A,
                                                  const bf16* __restrict__ W,
                                                  bf16* __restrict__ C) {
    const int bn = blockIdx.x & 31;
    const int bm = blockIdx.x >> 5;
    const int lane = threadIdx.x & 63;
    const int w = threadIdx.x >> 6;
    const int wm = (w >> 1) * 64, wn = (w & 1) * 64;
    const int lr = lane & 15;
    const int ko = (lane >> 4) * 8;

    const bf16* Abase = A + (size_t)(bm * 128 + wm + lr) * DIM + ko;
    const bf16* Wbase = W + (size_t)(bn * 128 + wn + lr) * DIM + ko;

    f32x4 acc[4][4] = {};
    for (int k = 0; k < DIM; k += 32) {
        bf16x8 af[4], bw[4];
#pragma unroll
        for (int m = 0; m < 4; ++m)
            af[m] = *(const bf16x8*)(Abase + (size_t)m * 16 * DIM + k);
#pragma unroll
        for (int n = 0; n < 4; ++n)
            bw[n] = *(const bf16x8*)(Wbase + (size_t)n * 16 * DIM + k);
#pragma unroll
        for (int m = 0; m < 4; ++m)
#pragma unroll
            for (int n = 0; n < 4; ++n)
                acc[m][n] = __builtin_amdgcn_mfma_f32_16x16x32_bf16(af[m], bw[n], acc[m][n], 0, 0, 0);
    }
    const int cr = (lane >> 4) * 4;
#pragma unroll
    for (int m = 0; m < 4; ++m)
#pragma unroll
        for (int n = 0; n < 4; ++n)
#pragma unroll
            for (int r = 0; r < 4; ++r) {
                int row = bm * 128 + wm + m * 16 + cr + r;
                int col = bn * 128 + wn + n * 16 + lr;
                C[(size_t)row * GATES + col] = __float2bfloat16(acc[m][n][r]);
            }
}

// -------------------------------------------------- persistent scan ------
// 2 domains (mi = batch half) x 64 blocks (g). Wave w = gate quadrant
// (i,f,g,o); block's gate cols = {w*1024 + g*16 + 0..15}. Block owns the
// c/h patch [16 batches of its half] x [hidden cols g*16..+16) -- gates,
// c, h all stay in registers; only per-batch partial sums and the h state
// cross blocks (LLC). 3 tag-synced exchanges per step.
__global__ __launch_bounds__(256) void scan_kernel(
    const bf16* __restrict__ gx,        // [T][B][4096] bf16
    const bf16* __restrict__ Wh_b,      // [4096][1024] bf16 (L2-resident)
    const float* __restrict__ c0,
    const float* __restrict__ gn_g, const float* __restrict__ gn_b,
    const float* __restrict__ cn_g, const float* __restrict__ cn_b,
    bf16* __restrict__ h_b,             // [B][H] recurrent state (coherent)
    float* __restrict__ out,
    float* __restrict__ h_final,
    float* __restrict__ c_final,
    u32* __restrict__ ex) {

    const int tid  = threadIdx.x;
    const int lane = tid & 63;
    const int w    = tid >> 6;           // gate quadrant 0..3 (i,f,g,o)
    const int mi   = blockIdx.x & 1;     // batch half
    const int g    = blockIdx.x >> 1;    // 0..63: hidden-col group
    const int ni   = w * 64 + g;         // 16-col gate tile id (0..255)
    const int lr   = lane & 15;          // A row / B row / acc col
    const int hi   = lane >> 4;
    const int ko   = hi * 8;
    const int cr   = hi * 4;             // acc row base (local batch)
    const int gcol = ni * 16 + lr;       // global gate col of both B-frag row and acc col
    const int ccol = g * 16 + lr;        // hidden col of this lane's patch

    // per-domain exchange state (32KB stride): gpart[16][64] u64, cpart
    // [16][64] u64, tags[64] u32 -- each block's partials fill ONE 128B line.
    u64* gpart = (u64*)(ex + (size_t)mi * 8192);
    u64* cpart = (u64*)(ex + (size_t)mi * 8192) + 1024;
    u32* tags  = ex + (size_t)mi * 8192 + 4096;

    __shared__ __align__(16) char hsm[16 * 2048];   // h half, XOR-swizzled
    __shared__ float lds_part[4][16][2];
    __shared__ float musd[16][2];
    __shared__ float musd2[16][2];
    __shared__ float lds_gate[4][16][17];           // +1 pad vs bank conflicts
    __shared__ __align__(16) u16 houts[256];        // 16x16 h patch staging

    const bf16* wbase = Wh_b + (size_t)gcol * HID + ko;
    const int arow = lr * 2048;
    const int axor = (lr & 7) << 4;

    // per-lane LN params (constant over t): gate col gcol, hidden col ccol
    const float gam = gn_g[gcol];
    const float bet = gn_b[gcol];
    float cng_ = 0.f, cnb_ = 0.f, creg[4];
    if (w == 0) {
        cng_ = cn_g[ccol];
        cnb_ = cn_b[ccol];
#pragma unroll
        for (int r = 0; r < 4; ++r)
            creg[r] = c0[(size_t)(mi * 16 + cr + r) * HID + ccol];
    }
    const u16* gxp = (const u16*)gx + ((size_t)(mi * 16 + cr) * GATES + gcol);

    for (int t = 0; t < T_STEPS; ++t) {
        // ---- gx prefetch (NT, HBM latency hides under stage+MFMA) ----
        u16 gxu[4];
        {
            const u16* gxt = gxp + (size_t)t * (BATCH * GATES);
#pragma unroll
            for (int r = 0; r < 4; ++r)
                gxu[r] = __builtin_nontemporal_load(gxt + (size_t)r * GATES);
        }

        // ---- stage h rows [mi*16,+16) into swizzled LDS (coherent reads) ----
        {
            const u64* hsrc = (const u64*)(h_b + (size_t)mi * 16 * HID);
#pragma unroll
            for (int u = 0; u < 16; ++u) {
                int i = u * 256 + tid;
                int row = i >> 8;                // 256 u64 per 2KB row
                int off8 = (i & 255) << 3;
                u64 v = ldc_u64(hsrc + i);
                *(u64*)(hsm + row * 2048 + (off8 ^ ((row & 7) << 4))) = v;
            }
        }
        __syncthreads();

        // ---- MFMA: 16 batches x 16 gate cols, K=1024 ----
        f32x4 acc = {0.f, 0.f, 0.f, 0.f};
#pragma unroll 8
        for (int kk = 0; kk < 32; ++kk) {
            bf16x8 a  = *(const bf16x8*)(hsm + arow + ((kk * 64 + ko * 2) ^ axor));
            bf16x8 bb = *(const bf16x8*)(wbase + kk * 32);
            acc = __builtin_amdgcn_mfma_f32_16x16x32_bf16(a, bb, acc, 0, 0, 0);
        }
        float G[4];
#pragma unroll
        for (int r = 0; r < 4; ++r) {
            union { u16 u; bf16 h; } cv; cv.u = gxu[r];
            G[r] = acc[r] + __bfloat162float(cv.h);
        }

        // ---- gates partial sums: reduce 16 cols (lane group), 4 quadrants ----
#pragma unroll
        for (int r = 0; r < 4; ++r) {
            float s = G[r], s2 = G[r] * G[r];
#pragma unroll
            for (int m = 1; m <= 8; m <<= 1) {
                s  += __shfl_xor(s, m, 64);
                s2 += __shfl_xor(s2, m, 64);
            }
            if (lr == 0) { lds_part[w][cr + r][0] = s; lds_part[w][cr + r][1] = s2; }
        }
        __syncthreads();
        if (w == 0) {
            if (lane < 16) {
                float s = 0.f, s2 = 0.f;
#pragma unroll
                for (int q = 0; q < 4; ++q) { s += lds_part[q][lane][0]; s2 += lds_part[q][lane][1]; }
                union { u64 u; float f[2]; } p; p.f[0] = s; p.f[1] = s2;
                stc_u64(gpart + lane * 64 + g, p.u);
            }
            asm volatile("s_waitcnt vmcnt(0)" ::: "memory");
            if (lane == 0) stc_u32(tags + g, 3u * t + 1u);
            wait_tags(tags, 3u * t + 1u);
        }
        __syncthreads();   // release: all 64 blocks' gates partials visible

        // ---- all-reduce read: wave w sums rows 4w..4w+3 over 64 blocks ----
#pragma unroll
        for (int q = 0; q < 4; ++q) {
            int row = 4 * w + q;
            union { u64 u; float f[2]; } p; p.u = ldc_u64(gpart + row * 64 + lane);
            float s = p.f[0], s2 = p.f[1];
#pragma unroll
            for (int m = 1; m <= 32; m <<= 1) {
                s  += __shfl_xor(s, m, 64);
                s2 += __shfl_xor(s2, m, 64);
            }
            if (lane == 0) {
                float mu = s * (1.0f / GATES);
                musd[row][0] = mu;
                musd[row][1] = rsqrtf(s2 * (1.0f / GATES) - mu * mu + 1e-5f);
            }
        }
        __syncthreads();

        // ---- apply gate LN; share f,g,o tiles via LDS ----
        float Gn[4];
#pragma unroll
        for (int r = 0; r < 4; ++r) {
            Gn[r] = (G[r] - musd[cr + r][0]) * musd[cr + r][1] * gam + bet;
            if (w) lds_gate[w][cr + r][lr] = Gn[r];
        }
        __syncthreads();

        // ---- wave0: c update + c partial sums ----
        float cnew[4];
        if (w == 0) {
#pragma unroll
            for (int r = 0; r < 4; ++r) {
                int row = cr + r;
                float fv = sigmf(lds_gate[1][row][lr]);
                float gv = tanhfast(lds_gate[2][row][lr]);
                float iv = sigmf(Gn[r]);
                cnew[r] = fv * creg[r] + iv * gv;
                float s = cnew[r], s2 = cnew[r] * cnew[r];
#pragma unroll
                for (int m = 1; m <= 8; m <<= 1) {
                    s  += __shfl_xor(s, m, 64);
                    s2 += __shfl_xor(s2, m, 64);
                }
                if (lr == 0) {
                    union { u64 u; float f[2]; } p; p.f[0] = s; p.f[1] = s2;
                    stc_u64(cpart + row * 64 + g, p.u);
                }
            }
            asm volatile("s_waitcnt vmcnt(0)" ::: "memory");
            if (lane == 0) stc_u32(tags + g, 3u * t + 2u);
            wait_tags(tags, 3u * t + 2u);
        }
        __syncthreads();   // release: all c partials visible

#pragma unroll
        for (int q = 0; q < 4; ++q) {
            int row = 4 * w + q;
            union { u64 u; float f[2]; } p; p.u = ldc_u64(cpart + row * 64 + lane);
            float s = p.f[0], s2 = p.f[1];
#pragma unroll
            for (int m = 1; m <= 32; m <<= 1) {
                s  += __shfl_xor(s, m, 64);
                s2 += __shfl_xor(s2, m, 64);
            }
            if (lane == 0) {
                float mu2 = s * (1.0f / HID);
                musd2[row][0] = mu2;
                musd2[row][1] = rsqrtf(s2 * (1.0f / HID) - mu2 * mu2 + 1e-5f);
            }
        }
        __syncthreads();

        // ---- wave0: c LN, h, publish ----
        if (w == 0) {
#pragma unroll
            for (int r = 0; r < 4; ++r) {
                int row = cr + r;
                float cn = (cnew[r] - musd2[row][0]) * musd2[row][1] * cng_ + cnb_;
                creg[r] = cn;
                float ov = sigmf(lds_gate[3][row][lr]);
                float hv = ov * tanhfast(cn);
                __builtin_nontemporal_store(hv,
                    out + ((size_t)t * BATCH + mi * 16 + row) * HID + ccol);
                houts[row * 16 + lr] = __bfloat16_as_ushort(__float2bfloat16(hv));
                if (t == T_STEPS - 1) {
                    h_final[(size_t)(mi * 16 + row) * HID + ccol] = hv;
                    c_final[(size_t)(mi * 16 + row) * HID + ccol] = cn;
                }
            }
            // pack patch -> coherent u64 stores: lane -> (row=lane>>2, 4 cols)
            u64 hv64 = *((const u64*)houts + lane);
            stc_u64((u64*)(h_b + (size_t)(mi * 16 + (lane >> 2)) * HID
                           + g * 16 + (lane & 3) * 4), hv64);
            asm volatile("s_waitcnt vmcnt(0)" ::: "memory");
            if (lane == 0) stc_u32(tags + g, 3u * t + 3u);
            wait_tags(tags, 3u * t + 3u);
        }
        __syncthreads();   // release: whole half's h(t) visible
    }
}

// ----------------------------------------------------------- launcher ----
extern "C" void kernel_launch(void* const* d_in, const int* in_sizes, int n_in,
                              void* d_out, int out_size, void* d_ws, size_t ws_size,
                              hipStream_t stream) {
    const float* input = (const float*)d_in[0];
    const float* h0    = (const float*)d_in[1];
    const float* c0    = (const float*)d_in[2];
    const float* Wx    = (const float*)d_in[3];
    const float* Wh    = (const float*)d_in[4];
    const float* gn_g  = (const float*)d_in[5];
    const float* gn_b  = (const float*)d_in[6];
    const float* cn_g  = (const float*)d_in[7];
    const float* cn_b  = (const float*)d_in[8];

    char* ws = (char*)d_ws;
    size_t off = 0;
    auto alloc = [&](size_t bytes) -> char* {
        char* p = ws + off;
        off += (bytes + 255) & ~(size_t)255;
        return p;
    };
    bf16* input_b = (bf16*)alloc((size_t)T_STEPS * BATCH * DIM * 2);
    bf16* Wx_b    = (bf16*)alloc((size_t)GATES * DIM * 2);
    bf16* Wh_b    = (bf16*)alloc((size_t)GATES * DIM * 2);
    bf16* gates_x = (bf16*)alloc((size_t)T_STEPS * BATCH * GATES * 2);
    bf16* h_b     = (bf16*)alloc((size_t)BATCH * HID * 2);
    off = (off + 4095) & ~(size_t)4095;
    u32* ex = (u32*)(ws + off);          // 2 domains x 32KB exchange state
    off += 65536;

    float* outp    = (float*)d_out;
    float* h_final = outp + (size_t)T_STEPS * BATCH * HID;
    float* c_final = h_final + (size_t)BATCH * HID;

    hipLaunchKernelGGL(prep_kernel, dim3(2048), dim3(256), 0, stream,
                       input, Wx, Wh, h0, input_b, Wx_b, Wh_b, h_b, ex);

    hipLaunchKernelGGL(gemm_input, dim3(4096), dim3(256), 0, stream,
                       input_b, Wx_b, gates_x);

    hipLaunchKernelGGL(scan_kernel, dim3(NBLK), dim3(256), 0, stream,
                       gates_x, Wh_b, c0, gn_g, gn_b, cn_g, cn_b,
                       h_b, outp, h_final, c_final, ex);
}

// Round 6
// 9276.986 us; speedup vs baseline: 1.2275x; 1.2275x over previous
//
#include <hip/hip_runtime.h>
#include <hip/hip_bf16.h>

typedef __hip_bfloat16 bf16;
typedef __attribute__((ext_vector_type(4))) float f32x4;
typedef __attribute__((ext_vector_type(8))) short bf16x8;
typedef unsigned long long u64;
typedef unsigned short u16;
typedef unsigned u32;

#define T_STEPS 512
#define BATCH   32
#define DIM     1024
#define HID     1024
#define GATES   4096
#define NBLK    128   // 2 halves x 64 blocks

static __device__ __forceinline__ float sigmf(float x) {
    return 1.0f / (1.0f + __expf(-x));
}
// overflow-safe tanh via exp: +/-inf exp -> correct +/-1, no NaN
static __device__ __forceinline__ float tanhfast(float x) {
    return 1.0f - 2.0f / (__expf(2.0f * x) + 1.0f);
}

// coherent (LLC-level) helpers: relaxed agent atomics -> sc-qualified ops,
// no cache-wide fences; L1/L2 stay warm for Wh/gx.
static __device__ __forceinline__ u64 ldc_u64(const u64* p) {
    return __hip_atomic_load((u64*)p, __ATOMIC_RELAXED, __HIP_MEMORY_SCOPE_AGENT);
}
static __device__ __forceinline__ void stc_u64(u64* p, u64 v) {
    __hip_atomic_store(p, v, __ATOMIC_RELAXED, __HIP_MEMORY_SCOPE_AGENT);
}
static __device__ __forceinline__ void stc_f32(float* p, float v) {
    __hip_atomic_store(p, v, __ATOMIC_RELAXED, __HIP_MEMORY_SCOPE_AGENT);
}
static __device__ __forceinline__ void stc_u32(u32* p, u32 v) {
    __hip_atomic_store(p, v, __ATOMIC_RELAXED, __HIP_MEMORY_SCOPE_AGENT);
}
static __device__ __forceinline__ u32 ldc_u32(const u32* p) {
    return __hip_atomic_load((u32*)p, __ATOMIC_RELAXED, __HIP_MEMORY_SCOPE_AGENT);
}

// ---------------------------------------------------------------- prep ----
__global__ void prep_kernel(const float* __restrict__ input,
                            const float* __restrict__ Wx,
                            const float* __restrict__ Wh,
                            const float* __restrict__ h0,
                            bf16* __restrict__ input_b,
                            bf16* __restrict__ Wx_b,
                            bf16* __restrict__ Wh_b,
                            bf16* __restrict__ h_b,
                            u32* __restrict__ ex) {
    const size_t NIN = (size_t)T_STEPS * BATCH * DIM;
    const size_t NW  = (size_t)GATES * DIM;
    const size_t NH  = (size_t)BATCH * HID;
    const size_t stride = (size_t)gridDim.x * blockDim.x;
    const size_t t0 = (size_t)blockIdx.x * blockDim.x + threadIdx.x;
    for (size_t i = t0; i < NIN; i += stride) input_b[i] = __float2bfloat16(input[i]);
    for (size_t i = t0; i < NW;  i += stride) Wx_b[i]    = __float2bfloat16(Wx[i]);
    for (size_t i = t0; i < NW;  i += stride) Wh_b[i]    = __float2bfloat16(Wh[i]);
    for (size_t i = t0; i < NH;  i += stride) h_b[i]     = __float2bfloat16(h0[i]);
    if (t0 < 2048) ex[t0] = 0u;   // 2 halves x 4KB tag state
}

// ------------------------------------------------- big GEMM: gates_x -----
__global__ __launch_bounds__(256) void gemm_input(const bf16* __restrict__ A,
                                                  const bf16* __restrict__ W,
                                                  bf16* __restrict__ C) {
    const int bn = blockIdx.x & 31;
    const int bm = blockIdx.x >> 5;
    const int lane = threadIdx.x & 63;
    const int w = threadIdx.x >> 6;
    const int wm = (w >> 1) * 64, wn = (w & 1) * 64;
    const int lr = lane & 15;
    const int ko = (lane >> 4) * 8;

    const bf16* Abase = A + (size_t)(bm * 128 + wm + lr) * DIM + ko;
    const bf16* Wbase = W + (size_t)(bn * 128 + wn + lr) * DIM + ko;

    f32x4 acc[4][4] = {};
    for (int k = 0; k < DIM; k += 32) {
        bf16x8 af[4], bw[4];
#pragma unroll
        for (int m = 0; m < 4; ++m)
            af[m] = *(const bf16x8*)(Abase + (size_t)m * 16 * DIM + k);
#pragma unroll
        for (int n = 0; n < 4; ++n)
            bw[n] = *(const bf16x8*)(Wbase + (size_t)n * 16 * DIM + k);
#pragma unroll
        for (int m = 0; m < 4; ++m)
#pragma unroll
            for (int n = 0; n < 4; ++n)
                acc[m][n] = __builtin_amdgcn_mfma_f32_16x16x32_bf16(af[m], bw[n], acc[m][n], 0, 0, 0);
    }
    const int cr = (lane >> 4) * 4;
#pragma unroll
    for (int m = 0; m < 4; ++m)
#pragma unroll
        for (int n = 0; n < 4; ++n)
#pragma unroll
            for (int r = 0; r < 4; ++r) {
                int row = bm * 128 + wm + m * 16 + cr + r;
                int col = bn * 128 + wn + n * 16 + lr;
                C[(size_t)row * GATES + col] = __float2bfloat16(acc[m][n][r]);
            }
}

static __device__ __forceinline__ void block_reduce2(float& s, float& s2,
                                                     float (*red)[4], int lane, int w) {
#pragma unroll
    for (int off = 32; off > 0; off >>= 1) {
        s  += __shfl_down(s, off, 64);
        s2 += __shfl_down(s2, off, 64);
    }
    if (lane == 0) { red[0][w] = s; red[1][w] = s2; }
    __syncthreads();
    s  = red[0][0] + red[0][1] + red[0][2] + red[0][3];
    s2 = red[1][0] + red[1][1] + red[1][2] + red[1][3];
    __syncthreads();
}

// -------------------------------------------------- persistent scan ------
// 2 halves (mi) x 64 blocks (g: 64 gate cols each). Sync = 2 direct flag
// hops per step, no leader:
//   hop1: 64 producers each store gates tile + own tag; 16 owners poll.
//   hop2: 16 owners publish h row + own tag; 64 producers poll 16 tags.
__global__ __launch_bounds__(256) void scan_kernel(
    const bf16* __restrict__ gx,        // [T][B][4096] bf16
    const bf16* __restrict__ Wh_b,      // [4096][1024] bf16 (L2-resident)
    const float* __restrict__ c0,
    const float* __restrict__ gn_g, const float* __restrict__ gn_b,
    const float* __restrict__ cn_g, const float* __restrict__ cn_b,
    bf16* __restrict__ h_b,             // [B][H] recurrent state (coherent)
    float* __restrict__ gates_pre,      // [B][4096] scratch (coherent)
    float* __restrict__ out,
    float* __restrict__ h_final,
    float* __restrict__ c_final,
    u32* __restrict__ ex) {

    const int tid  = threadIdx.x;
    const int lane = tid & 63;
    const int w    = tid >> 6;
    const int mi   = blockIdx.x & 1;     // batch half: rows mi*16..+16
    const int g    = blockIdx.x >> 1;    // 0..63: gate cols [g*64, +64)
    const int ni   = g * 4 + w;          // this wave's 16-col tile
    const int lr   = lane & 15;
    const int ko   = (lane >> 4) * 8;
    const int cr   = (lane >> 4) * 4;
    const int gcol = ni * 16 + lr;
    const int brow = mi * 16 + cr;

    // per-half tag state (4KB stride): ptags[64] (256B) then otags[16] (64B,
    // its own line at +512B)
    u32* ptags = ex + mi * 1024;
    u32* otags = ex + mi * 1024 + 128;

    __shared__ __align__(16) char hsm[16 * 2048];   // 16 rows x 1024 bf16, XOR-swizzled
    __shared__ float red[2][4];

    const bf16* wbase = Wh_b + (size_t)gcol * HID + ko;   // normal cached
    const int arow = lr * 2048;
    const int axor = (lr & 7) << 4;

    // owner of batch b = mi*16+g iff g<16; c kept in registers (elems 4*tid+q)
    const bool owner = (g < 16);
    const int b = mi * 16 + g;
    float creg[4];
    if (owner) {
#pragma unroll
        for (int q = 0; q < 4; ++q) creg[q] = c0[b * HID + 4 * tid + q];
    }

    // gx prefetch for t=0
    const u16* gxp0 = (const u16*)gx + ((size_t)brow * GATES + gcol);
    u16 gxu[4];
#pragma unroll
    for (int r = 0; r < 4; ++r)
        gxu[r] = __builtin_nontemporal_load(gxp0 + (size_t)r * GATES);

    for (int t = 0; t < T_STEPS; ++t) {
        // ---- stage h rows [mi*16,+16) into swizzled LDS (coherent) ----
        {
            const u64* hsrc = (const u64*)(h_b + (size_t)mi * 16 * HID);
#pragma unroll
            for (int u = 0; u < 16; ++u) {
                int i = u * 256 + tid;
                int row = i >> 8;                // 256 u64 per 2KB row
                int off8 = (i & 255) << 3;
                u64 v = ldc_u64(hsrc + i);
                *(u64*)(hsm + row * 2048 + (off8 ^ ((row & 7) << 4))) = v;
            }
        }
        __syncthreads();

        // ---- MFMA: 16 batches x 16 gate cols, K=1024; add gx; publish ----
        {
            f32x4 acc = {0.f, 0.f, 0.f, 0.f};
#pragma unroll 8
            for (int kk = 0; kk < 32; ++kk) {
                bf16x8 a  = *(const bf16x8*)(hsm + arow + ((kk * 64 + ko * 2) ^ axor));
                bf16x8 bb = *(const bf16x8*)(wbase + kk * 32);
                acc = __builtin_amdgcn_mfma_f32_16x16x32_bf16(a, bb, acc, 0, 0, 0);
            }
            float* gp = gates_pre + (size_t)brow * GATES + gcol;
#pragma unroll
            for (int r = 0; r < 4; ++r) {
                union { u16 u; bf16 h; } cv; cv.u = gxu[r];
                stc_f32(gp + (size_t)r * GATES, acc[r] + __bfloat162float(cv.h));
            }
        }
        // hop1 release: drain this wave's stores, block-sync, store own tag
        asm volatile("s_waitcnt vmcnt(0)" ::: "memory");
        __syncthreads();
        if (tid == 0) stc_u32(ptags + g, (u32)(t + 1));

        // ---- owners: wait for all 64 producer tags, then LN + cell ----
        if (owner) {
            if (w == 0) {
                u32 v = ldc_u32(ptags + lane);
                while (!__all((int)(v >= (u32)(t + 1))))
                    v = ldc_u32(ptags + lane);
            }
            __syncthreads();

            const u64* grow = (const u64*)(gates_pre + (size_t)b * GATES);
            float gv_[4][4];
            float s = 0.f, s2 = 0.f;
#pragma unroll
            for (int gq = 0; gq < 4; ++gq) {
                union { u64 u; float f[2]; } v0, v1;
                v0.u = ldc_u64(grow + gq * 512 + 2 * tid);
                v1.u = ldc_u64(grow + gq * 512 + 2 * tid + 1);
                gv_[gq][0] = v0.f[0]; gv_[gq][1] = v0.f[1];
                gv_[gq][2] = v1.f[0]; gv_[gq][3] = v1.f[1];
#pragma unroll
                for (int q = 0; q < 4; ++q) { s += gv_[gq][q]; s2 += gv_[gq][q] * gv_[gq][q]; }
            }
            block_reduce2(s, s2, red, lane, w);
            const float mu   = s * (1.0f / GATES);
            const float rstd = rsqrtf(s2 * (1.0f / GATES) - mu * mu + 1e-5f);

            float ov[4], cn_[4];
            float cs = 0.f, cs2 = 0.f;
#pragma unroll
            for (int q = 0; q < 4; ++q) {
                int j = 4 * tid + q;
                float iv = sigmf(   (gv_[0][q] - mu) * rstd * gn_g[j]           + gn_b[j]);
                float fv = sigmf(   (gv_[1][q] - mu) * rstd * gn_g[HID + j]     + gn_b[HID + j]);
                float gg = tanhfast((gv_[2][q] - mu) * rstd * gn_g[2 * HID + j] + gn_b[2 * HID + j]);
                ov[q] =             (gv_[3][q] - mu) * rstd * gn_g[3 * HID + j] + gn_b[3 * HID + j];
                float cnew = fv * creg[q] + iv * gg;
                cn_[q] = cnew;
                cs += cnew; cs2 += cnew * cnew;
            }
            block_reduce2(cs, cs2, red, lane, w);
            const float mu2   = cs * (1.0f / HID);
            const float rstd2 = rsqrtf(cs2 * (1.0f / HID) - mu2 * mu2 + 1e-5f);

            float* orow = out + ((size_t)t * BATCH + b) * HID + 4 * tid;
            union { u64 u; unsigned short h[4]; } hpack;
#pragma unroll
            for (int q = 0; q < 4; ++q) {
                int j = 4 * tid + q;
                float cn = (cn_[q] - mu2) * rstd2 * cn_g[j] + cn_b[j];
                creg[q] = cn;
                float hv = sigmf(ov[q]) * tanhfast(cn);
                __builtin_nontemporal_store(hv, orow + q);     // don't evict Wh
                hpack.h[q] = __bfloat16_as_ushort(__float2bfloat16(hv));
                if (t == T_STEPS - 1) {
                    h_final[b * HID + j] = hv;
                    c_final[b * HID + j] = cn;
                }
            }
            stc_u64((u64*)(h_b + (size_t)b * HID + 4 * tid), hpack.u);  // publish
            // hop2 release: drain, block-sync, store own owner-tag
            asm volatile("s_waitcnt vmcnt(0)" ::: "memory");
            __syncthreads();
            if (tid == 0) stc_u32(otags + g, (u32)(t + 1));
        }

        // ---- prefetch gx(t+1) while waiting for h(t) ----
        if (t + 1 < T_STEPS) {
            const u16* gxt = gxp0 + (size_t)(t + 1) * (BATCH * GATES);
#pragma unroll
            for (int r = 0; r < 4; ++r)
                gxu[r] = __builtin_nontemporal_load(gxt + (size_t)r * GATES);
        }

        // ---- hop2 wait: all 16 owner tags of this half ----
        if (w == 0) {
            u32 v = ldc_u32(otags + (lane & 15));
            while (!__all((int)(v >= (u32)(t + 1)))) {
                __builtin_amdgcn_s_sleep(1);
                v = ldc_u32(otags + (lane & 15));
            }
        }
        __syncthreads();
    }
}

// ----------------------------------------------------------- launcher ----
extern "C" void kernel_launch(void* const* d_in, const int* in_sizes, int n_in,
                              void* d_out, int out_size, void* d_ws, size_t ws_size,
                              hipStream_t stream) {
    const float* input = (const float*)d_in[0];
    const float* h0    = (const float*)d_in[1];
    const float* c0    = (const float*)d_in[2];
    const float* Wx    = (const float*)d_in[3];
    const float* Wh    = (const float*)d_in[4];
    const float* gn_g  = (const float*)d_in[5];
    const float* gn_b  = (const float*)d_in[6];
    const float* cn_g  = (const float*)d_in[7];
    const float* cn_b  = (const float*)d_in[8];

    char* ws = (char*)d_ws;
    size_t off = 0;
    auto alloc = [&](size_t bytes) -> char* {
        char* p = ws + off;
        off += (bytes + 255) & ~(size_t)255;
        return p;
    };
    bf16*  input_b   = (bf16*) alloc((size_t)T_STEPS * BATCH * DIM * 2);
    bf16*  Wx_b      = (bf16*) alloc((size_t)GATES * DIM * 2);
    bf16*  Wh_b      = (bf16*) alloc((size_t)GATES * DIM * 2);
    bf16*  gates_x   = (bf16*) alloc((size_t)T_STEPS * BATCH * GATES * 2);
    float* gates_pre = (float*)alloc((size_t)BATCH * GATES * 4);
    bf16*  h_b       = (bf16*) alloc((size_t)BATCH * HID * 2);
    off = (off + 4095) & ~(size_t)4095;
    u32* ex = (u32*)(ws + off);          // 2 halves x 4KB tag state
    off += 8192;

    float* outp    = (float*)d_out;
    float* h_final = outp + (size_t)T_STEPS * BATCH * HID;
    float* c_final = h_final + (size_t)BATCH * HID;

    hipLaunchKernelGGL(prep_kernel, dim3(2048), dim3(256), 0, stream,
                       input, Wx, Wh, h0, input_b, Wx_b, Wh_b, h_b, ex);

    hipLaunchKernelGGL(gemm_input, dim3(4096), dim3(256), 0, stream,
                       input_b, Wx_b, gates_x);

    hipLaunchKernelGGL(scan_kernel, dim3(NBLK), dim3(256), 0, stream,
                       gates_x, Wh_b, c0, gn_g, gn_b, cn_g, cn_b,
                       h_b, gates_pre, outp, h_final, c_final, ex);
}

// Round 7
// 6024.308 us; speedup vs baseline: 1.8902x; 1.5399x over previous
//
#include <hip/hip_runtime.h>
#include <hip/hip_bf16.h>

typedef __hip_bfloat16 bf16;
typedef __attribute__((ext_vector_type(4))) float f32x4;
typedef __attribute__((ext_vector_type(8))) short bf16x8;
typedef unsigned long long u64;
typedef unsigned short u16;
typedef unsigned u32;

#define T_STEPS 512
#define BATCH   32
#define DIM     1024
#define HID     1024
#define GATES   4096
#define NBLK    64    // 2 halves x 32 blocks, 512 threads each

static __device__ __forceinline__ float sigmf(float x) {
    return 1.0f / (1.0f + __expf(-x));
}
// overflow-safe tanh via exp: +/-inf exp -> correct +/-1, no NaN
static __device__ __forceinline__ float tanhfast(float x) {
    return 1.0f - 2.0f / (__expf(2.0f * x) + 1.0f);
}

// coherent (LLC-level) helpers: relaxed agent atomics -> sc-qualified ops,
// no cache-wide fences; L1/L2 stay warm for Wh/gx.
static __device__ __forceinline__ u64 ldc_u64(const u64* p) {
    return __hip_atomic_load((u64*)p, __ATOMIC_RELAXED, __HIP_MEMORY_SCOPE_AGENT);
}
static __device__ __forceinline__ void stc_u64(u64* p, u64 v) {
    __hip_atomic_store(p, v, __ATOMIC_RELAXED, __HIP_MEMORY_SCOPE_AGENT);
}
static __device__ __forceinline__ void stc_f32(float* p, float v) {
    __hip_atomic_store(p, v, __ATOMIC_RELAXED, __HIP_MEMORY_SCOPE_AGENT);
}
static __device__ __forceinline__ void stc_u32(u32* p, u32 v) {
    __hip_atomic_store(p, v, __ATOMIC_RELAXED, __HIP_MEMORY_SCOPE_AGENT);
}
static __device__ __forceinline__ u32 ldc_u32(const u32* p) {
    return __hip_atomic_load((u32*)p, __ATOMIC_RELAXED, __HIP_MEMORY_SCOPE_AGENT);
}

// ---------------------------------------------------------------- prep ----
__global__ void prep_kernel(const float* __restrict__ input,
                            const float* __restrict__ Wx,
                            const float* __restrict__ Wh,
                            const float* __restrict__ h0,
                            bf16* __restrict__ input_b,
                            bf16* __restrict__ Wx_b,
                            bf16* __restrict__ Wh_b,
                            bf16* __restrict__ h_b,
                            u32* __restrict__ ex) {
    const size_t NIN = (size_t)T_STEPS * BATCH * DIM;
    const size_t NW  = (size_t)GATES * DIM;
    const size_t NH  = (size_t)BATCH * HID;
    const size_t stride = (size_t)gridDim.x * blockDim.x;
    const size_t t0 = (size_t)blockIdx.x * blockDim.x + threadIdx.x;
    for (size_t i = t0; i < NIN; i += stride) input_b[i] = __float2bfloat16(input[i]);
    for (size_t i = t0; i < NW;  i += stride) Wx_b[i]    = __float2bfloat16(Wx[i]);
    for (size_t i = t0; i < NW;  i += stride) Wh_b[i]    = __float2bfloat16(Wh[i]);
    for (size_t i = t0; i < NH;  i += stride) h_b[i]     = __float2bfloat16(h0[i]);
    if (t0 < 2048) ex[t0] = 0u;   // 2 halves x 4KB tag state
}

// ------------------------------------------------- big GEMM: gates_x -----
__global__ __launch_bounds__(256) void gemm_input(const bf16* __restrict__ A,
                                                  const bf16* __restrict__ W,
                                                  bf16* __restrict__ C) {
    const int bn = blockIdx.x & 31;
    const int bm = blockIdx.x >> 5;
    const int lane = threadIdx.x & 63;
    const int w = threadIdx.x >> 6;
    const int wm = (w >> 1) * 64, wn = (w & 1) * 64;
    const int lr = lane & 15;
    const int ko = (lane >> 4) * 8;

    const bf16* Abase = A + (size_t)(bm * 128 + wm + lr) * DIM + ko;
    const bf16* Wbase = W + (size_t)(bn * 128 + wn + lr) * DIM + ko;

    f32x4 acc[4][4] = {};
    for (int k = 0; k < DIM; k += 32) {
        bf16x8 af[4], bw[4];
#pragma unroll
        for (int m = 0; m < 4; ++m)
            af[m] = *(const bf16x8*)(Abase + (size_t)m * 16 * DIM + k);
#pragma unroll
        for (int n = 0; n < 4; ++n)
            bw[n] = *(const bf16x8*)(Wbase + (size_t)n * 16 * DIM + k);
#pragma unroll
        for (int m = 0; m < 4; ++m)
#pragma unroll
            for (int n = 0; n < 4; ++n)
                acc[m][n] = __builtin_amdgcn_mfma_f32_16x16x32_bf16(af[m], bw[n], acc[m][n], 0, 0, 0);
    }
    const int cr = (lane >> 4) * 4;
#pragma unroll
    for (int m = 0; m < 4; ++m)
#pragma unroll
        for (int n = 0; n < 4; ++n)
#pragma unroll
            for (int r = 0; r < 4; ++r) {
                int row = bm * 128 + wm + m * 16 + cr + r;
                int col = bn * 128 + wn + n * 16 + lr;
                C[(size_t)row * GATES + col] = __float2bfloat16(acc[m][n][r]);
            }
}

// 8-wave block reduce (sum, sumsq)
static __device__ __forceinline__ void block_reduce2(float& s, float& s2,
                                                     float (*red)[8], int lane, int w) {
#pragma unroll
    for (int off = 32; off > 0; off >>= 1) {
        s  += __shfl_down(s, off, 64);
        s2 += __shfl_down(s2, off, 64);
    }
    if (lane == 0) { red[0][w] = s; red[1][w] = s2; }
    __syncthreads();
    s  = red[0][0] + red[0][1] + red[0][2] + red[0][3]
       + red[0][4] + red[0][5] + red[0][6] + red[0][7];
    s2 = red[1][0] + red[1][1] + red[1][2] + red[1][3]
       + red[1][4] + red[1][5] + red[1][6] + red[1][7];
    __syncthreads();
}

// -------------------------------------------------- persistent scan ------
// 2 halves (mi) x 32 blocks (g: 128 gate cols each, 8 waves). Wh slice for
// each wave persists in VGPRs (constant over t). Sync = 2 direct flag hops:
//   hop1: 32 producers store gates tiles + own tag; 16 owners poll 32 tags.
//   hop2: 16 owners publish h row + own tag; producers poll 16 tags.
__global__ __launch_bounds__(512, 2) void scan_kernel(
    const bf16* __restrict__ gx,        // [T][B][4096] bf16
    const bf16* __restrict__ Wh_b,      // [4096][1024] bf16
    const float* __restrict__ c0,
    const float* __restrict__ gn_g, const float* __restrict__ gn_b,
    const float* __restrict__ cn_g, const float* __restrict__ cn_b,
    bf16* __restrict__ h_b,             // [B][H] recurrent state (coherent)
    float* __restrict__ gates_pre,      // [B][4096] scratch (coherent)
    float* __restrict__ out,
    float* __restrict__ h_final,
    float* __restrict__ c_final,
    u32* __restrict__ ex) {

    const int tid  = threadIdx.x;
    const int lane = tid & 63;
    const int w    = tid >> 6;           // 0..7
    const int mi   = blockIdx.x & 1;     // batch half: rows mi*16..+16
    const int g    = blockIdx.x >> 1;    // 0..31: gate cols [g*128, +128)
    const int ni   = g * 8 + w;          // this wave's 16-col tile (0..255)
    const int lr   = lane & 15;
    const int hi   = lane >> 4;
    const int ko   = hi * 8;
    const int cr   = hi * 4;
    const int gcol = ni * 16 + lr;
    const int brow = mi * 16 + cr;

    u32* ptags = ex + mi * 1024;         // 32 producer tags (128B)
    u32* otags = ex + mi * 1024 + 128;   // 16 owner tags (own line, +512B)

    __shared__ __align__(16) char hsm[16 * 2048];   // 16 rows x 1024 bf16, XOR-swizzled
    __shared__ float red[2][8];

    // ---- persist this wave's Wh slice (16 cols x 1024 K) in 128 VGPRs ----
    const bf16* wbase = Wh_b + (size_t)gcol * HID + ko;
    bf16x8 bfrag[32];
#pragma unroll
    for (int kk = 0; kk < 32; ++kk)
        bfrag[kk] = *(const bf16x8*)(wbase + kk * 32);

    const int arow = lr * 2048;
    const int axor = (lr & 7) << 4;

    // owner of batch b = mi*16+g iff g<16; c in registers (elems 2*tid+q)
    const bool owner = (g < 16);
    const int b = mi * 16 + g;
    float creg[2];
    if (owner) {
#pragma unroll
        for (int q = 0; q < 2; ++q) creg[q] = c0[b * HID + 2 * tid + q];
    }

    // gx prefetch for t=0
    const u16* gxp0 = (const u16*)gx + ((size_t)brow * GATES + gcol);
    u16 gxu[4];
#pragma unroll
    for (int r = 0; r < 4; ++r)
        gxu[r] = __builtin_nontemporal_load(gxp0 + (size_t)r * GATES);

    for (int t = 0; t < T_STEPS; ++t) {
        // ---- stage h rows [mi*16,+16) into swizzled LDS (coherent) ----
        {
            const u64* hsrc = (const u64*)(h_b + (size_t)mi * 16 * HID);
#pragma unroll
            for (int u = 0; u < 8; ++u) {
                int i = u * 512 + tid;
                int row = i >> 8;                // 256 u64 per 2KB row
                int off8 = (i & 255) << 3;
                u64 v = ldc_u64(hsrc + i);
                *(u64*)(hsm + row * 2048 + (off8 ^ ((row & 7) << 4))) = v;
            }
        }
        __syncthreads();

        // ---- MFMA: 16 batches x 16 gate cols, K=1024 (B from VGPRs) ----
        {
            f32x4 acc = {0.f, 0.f, 0.f, 0.f};
#pragma unroll
            for (int kk = 0; kk < 32; ++kk) {
                bf16x8 a = *(const bf16x8*)(hsm + arow + ((kk * 64 + ko * 2) ^ axor));
                acc = __builtin_amdgcn_mfma_f32_16x16x32_bf16(a, bfrag[kk], acc, 0, 0, 0);
            }
            float* gp = gates_pre + (size_t)brow * GATES + gcol;
#pragma unroll
            for (int r = 0; r < 4; ++r) {
                union { u16 u; bf16 h; } cv; cv.u = gxu[r];
                stc_f32(gp + (size_t)r * GATES, acc[r] + __bfloat162float(cv.h));
            }
        }
        // hop1 release: drain stores, block-sync, store own tag
        asm volatile("s_waitcnt vmcnt(0)" ::: "memory");
        __syncthreads();
        if (tid == 0) stc_u32(ptags + g, (u32)(t + 1));

        // ---- owners: wait for all 32 producer tags, then LN + cell ----
        if (owner) {
            if (w == 0) {
                u32 v = (lane < 32) ? ldc_u32(ptags + lane) : 0xFFFFFFFFu;
                while (!__all((int)(v >= (u32)(t + 1))))
                    v = (lane < 32) ? ldc_u32(ptags + lane) : 0xFFFFFFFFu;
            }
            __syncthreads();

            const u64* grow = (const u64*)(gates_pre + (size_t)b * GATES);
            float gv_[4][2];
            float s = 0.f, s2 = 0.f;
#pragma unroll
            for (int gq = 0; gq < 4; ++gq) {
                union { u64 u; float f[2]; } v0;
                v0.u = ldc_u64(grow + gq * 512 + tid);
                gv_[gq][0] = v0.f[0]; gv_[gq][1] = v0.f[1];
#pragma unroll
                for (int q = 0; q < 2; ++q) { s += gv_[gq][q]; s2 += gv_[gq][q] * gv_[gq][q]; }
            }
            block_reduce2(s, s2, red, lane, w);
            const float mu   = s * (1.0f / GATES);
            const float rstd = rsqrtf(s2 * (1.0f / GATES) - mu * mu + 1e-5f);

            float ov[2], cn_[2];
            float cs = 0.f, cs2 = 0.f;
#pragma unroll
            for (int q = 0; q < 2; ++q) {
                int j = 2 * tid + q;
                float iv = sigmf(   (gv_[0][q] - mu) * rstd * gn_g[j]           + gn_b[j]);
                float fv = sigmf(   (gv_[1][q] - mu) * rstd * gn_g[HID + j]     + gn_b[HID + j]);
                float gg = tanhfast((gv_[2][q] - mu) * rstd * gn_g[2 * HID + j] + gn_b[2 * HID + j]);
                ov[q] =             (gv_[3][q] - mu) * rstd * gn_g[3 * HID + j] + gn_b[3 * HID + j];
                float cnew = fv * creg[q] + iv * gg;
                cn_[q] = cnew;
                cs += cnew; cs2 += cnew * cnew;
            }
            block_reduce2(cs, cs2, red, lane, w);
            const float mu2   = cs * (1.0f / HID);
            const float rstd2 = rsqrtf(cs2 * (1.0f / HID) - mu2 * mu2 + 1e-5f);

            float* orow = out + ((size_t)t * BATCH + b) * HID + 2 * tid;
            union { u32 u; unsigned short h[2]; } hpack;
#pragma unroll
            for (int q = 0; q < 2; ++q) {
                int j = 2 * tid + q;
                float cn = (cn_[q] - mu2) * rstd2 * cn_g[j] + cn_b[j];
                creg[q] = cn;
                float hv = sigmf(ov[q]) * tanhfast(cn);
                __builtin_nontemporal_store(hv, orow + q);     // don't evict caches
                hpack.h[q] = __bfloat16_as_ushort(__float2bfloat16(hv));
                if (t == T_STEPS - 1) {
                    h_final[b * HID + j] = hv;
                    c_final[b * HID + j] = cn;
                }
            }
            stc_u32((u32*)(h_b + (size_t)b * HID + 2 * tid), hpack.u);  // publish
            // hop2 release: drain, block-sync, store own owner-tag
            asm volatile("s_waitcnt vmcnt(0)" ::: "memory");
            __syncthreads();
            if (tid == 0) stc_u32(otags + g, (u32)(t + 1));
        }

        // ---- prefetch gx(t+1) while waiting for h(t) ----
        if (t + 1 < T_STEPS) {
            const u16* gxt = gxp0 + (size_t)(t + 1) * (BATCH * GATES);
#pragma unroll
            for (int r = 0; r < 4; ++r)
                gxu[r] = __builtin_nontemporal_load(gxt + (size_t)r * GATES);
        }

        // ---- hop2 wait: all 16 owner tags of this half ----
        if (w == 0) {
            u32 v = ldc_u32(otags + (lane & 15));
            while (!__all((int)(v >= (u32)(t + 1)))) {
                __builtin_amdgcn_s_sleep(1);
                v = ldc_u32(otags + (lane & 15));
            }
        }
        __syncthreads();
    }
}

// ----------------------------------------------------------- launcher ----
extern "C" void kernel_launch(void* const* d_in, const int* in_sizes, int n_in,
                              void* d_out, int out_size, void* d_ws, size_t ws_size,
                              hipStream_t stream) {
    const float* input = (const float*)d_in[0];
    const float* h0    = (const float*)d_in[1];
    const float* c0    = (const float*)d_in[2];
    const float* Wx    = (const float*)d_in[3];
    const float* Wh    = (const float*)d_in[4];
    const float* gn_g  = (const float*)d_in[5];
    const float* gn_b  = (const float*)d_in[6];
    const float* cn_g  = (const float*)d_in[7];
    const float* cn_b  = (const float*)d_in[8];

    char* ws = (char*)d_ws;
    size_t off = 0;
    auto alloc = [&](size_t bytes) -> char* {
        char* p = ws + off;
        off += (bytes + 255) & ~(size_t)255;
        return p;
    };
    bf16*  input_b   = (bf16*) alloc((size_t)T_STEPS * BATCH * DIM * 2);
    bf16*  Wx_b      = (bf16*) alloc((size_t)GATES * DIM * 2);
    bf16*  Wh_b      = (bf16*) alloc((size_t)GATES * DIM * 2);
    bf16*  gates_x   = (bf16*) alloc((size_t)T_STEPS * BATCH * GATES * 2);
    float* gates_pre = (float*)alloc((size_t)BATCH * GATES * 4);
    bf16*  h_b       = (bf16*) alloc((size_t)BATCH * HID * 2);
    off = (off + 4095) & ~(size_t)4095;
    u32* ex = (u32*)(ws + off);          // 2 halves x 4KB tag state
    off += 8192;

    float* outp    = (float*)d_out;
    float* h_final = outp + (size_t)T_STEPS * BATCH * HID;
    float* c_final = h_final + (size_t)BATCH * HID;

    hipLaunchKernelGGL(prep_kernel, dim3(2048), dim3(256), 0, stream,
                       input, Wx, Wh, h0, input_b, Wx_b, Wh_b, h_b, ex);

    hipLaunchKernelGGL(gemm_input, dim3(4096), dim3(256), 0, stream,
                       input_b, Wx_b, gates_x);

    hipLaunchKernelGGL(scan_kernel, dim3(NBLK), dim3(512), 0, stream,
                       gates_x, Wh_b, c0, gn_g, gn_b, cn_g, cn_b,
                       h_b, gates_pre, outp, h_final, c_final, ex);
}

// Round 8
// 5625.090 us; speedup vs baseline: 2.0244x; 1.0710x over previous
//
#include <hip/hip_runtime.h>
#include <hip/hip_bf16.h>

typedef __hip_bfloat16 bf16;
typedef __attribute__((ext_vector_type(4))) float f32x4;
typedef __attribute__((ext_vector_type(8))) short bf16x8;
typedef unsigned long long u64;
typedef unsigned short u16;
typedef unsigned u32;

#define T_STEPS 512
#define BATCH   32
#define DIM     1024
#define HID     1024
#define GATES   4096
#define NBLK    64    // 2 halves x 32 blocks, 512 threads each

static __device__ __forceinline__ float sigmf(float x) {
    return 1.0f / (1.0f + __expf(-x));
}
// overflow-safe tanh via exp: +/-inf exp -> correct +/-1, no NaN
static __device__ __forceinline__ float tanhfast(float x) {
    return 1.0f - 2.0f / (__expf(2.0f * x) + 1.0f);
}

// coherent (LLC-level) helpers: relaxed agent atomics -> sc-qualified ops,
// no cache-wide fences; L1/L2 stay warm for Wh/gx.
static __device__ __forceinline__ u64 ldc_u64(const u64* p) {
    return __hip_atomic_load((u64*)p, __ATOMIC_RELAXED, __HIP_MEMORY_SCOPE_AGENT);
}
static __device__ __forceinline__ void stc_f32(float* p, float v) {
    __hip_atomic_store(p, v, __ATOMIC_RELAXED, __HIP_MEMORY_SCOPE_AGENT);
}
static __device__ __forceinline__ void stc_u32(u32* p, u32 v) {
    __hip_atomic_store(p, v, __ATOMIC_RELAXED, __HIP_MEMORY_SCOPE_AGENT);
}
static __device__ __forceinline__ u32 ldc_u32(const u32* p) {
    return __hip_atomic_load((u32*)p, __ATOMIC_RELAXED, __HIP_MEMORY_SCOPE_AGENT);
}

// ---------------------------------------------------------------- prep ----
__global__ void prep_kernel(const float* __restrict__ input,
                            const float* __restrict__ Wx,
                            const float* __restrict__ Wh,
                            const float* __restrict__ h0,
                            bf16* __restrict__ input_b,
                            bf16* __restrict__ Wx_b,
                            bf16* __restrict__ Wh_b,
                            bf16* __restrict__ h_b,
                            u32* __restrict__ ex) {
    const size_t NIN = (size_t)T_STEPS * BATCH * DIM;
    const size_t NW  = (size_t)GATES * DIM;
    const size_t NH  = (size_t)BATCH * HID;
    const size_t stride = (size_t)gridDim.x * blockDim.x;
    const size_t t0 = (size_t)blockIdx.x * blockDim.x + threadIdx.x;
    for (size_t i = t0; i < NIN; i += stride) input_b[i] = __float2bfloat16(input[i]);
    for (size_t i = t0; i < NW;  i += stride) Wx_b[i]    = __float2bfloat16(Wx[i]);
    for (size_t i = t0; i < NW;  i += stride) Wh_b[i]    = __float2bfloat16(Wh[i]);
    for (size_t i = t0; i < NH;  i += stride) h_b[i]     = __float2bfloat16(h0[i]);
    if (t0 < 2048) ex[t0] = 0u;   // 2 halves x 4KB tag state (every launch)
}

// ------------------------------------------------- big GEMM: gates_x -----
__global__ __launch_bounds__(256) void gemm_input(const bf16* __restrict__ A,
                                                  const bf16* __restrict__ W,
                                                  bf16* __restrict__ C) {
    const int bn = blockIdx.x & 31;
    const int bm = blockIdx.x >> 5;
    const int lane = threadIdx.x & 63;
    const int w = threadIdx.x >> 6;
    const int wm = (w >> 1) * 64, wn = (w & 1) * 64;
    const int lr = lane & 15;
    const int ko = (lane >> 4) * 8;

    const bf16* Abase = A + (size_t)(bm * 128 + wm + lr) * DIM + ko;
    const bf16* Wbase = W + (size_t)(bn * 128 + wn + lr) * DIM + ko;

    f32x4 acc[4][4] = {};
    for (int k = 0; k < DIM; k += 32) {
        bf16x8 af[4], bw[4];
#pragma unroll
        for (int m = 0; m < 4; ++m)
            af[m] = *(const bf16x8*)(Abase + (size_t)m * 16 * DIM + k);
#pragma unroll
        for (int n = 0; n < 4; ++n)
            bw[n] = *(const bf16x8*)(Wbase + (size_t)n * 16 * DIM + k);
#pragma unroll
        for (int m = 0; m < 4; ++m)
#pragma unroll
            for (int n = 0; n < 4; ++n)
                acc[m][n] = __builtin_amdgcn_mfma_f32_16x16x32_bf16(af[m], bw[n], acc[m][n], 0, 0, 0);
    }
    const int cr = (lane >> 4) * 4;
#pragma unroll
    for (int m = 0; m < 4; ++m)
#pragma unroll
        for (int n = 0; n < 4; ++n)
#pragma unroll
            for (int r = 0; r < 4; ++r) {
                int row = bm * 128 + wm + m * 16 + cr + r;
                int col = bn * 128 + wn + n * 16 + lr;
                C[(size_t)row * GATES + col] = __float2bfloat16(acc[m][n][r]);
            }
}

// -------------------------------------------------- persistent scan ------
// 2 halves (mi) x 32 blocks (g). 8 waves x 512 threads. Wh slices persist
// in VGPR/AGPR. Per step: [per-wave poll+stage h rows] -> MFMA -> gates
// publish + ptag -> owners (g<16): per-wave poll 4 ptags + read 2KB slices
// with on-the-fly LN sums into LDS gbuf -> LN + cell + c-reduce -> h publish
// + otag -> deferred out stores. No global hop2 wait (folded into stage).
__global__ __launch_bounds__(512, 2) void scan_kernel(
    const bf16* __restrict__ gx,        // [T][B][4096] bf16
    const bf16* __restrict__ Wh_b,      // [4096][1024] bf16
    const float* __restrict__ c0,
    const float* __restrict__ gn_g, const float* __restrict__ gn_b,
    const float* __restrict__ cn_g, const float* __restrict__ cn_b,
    bf16* __restrict__ h_b,             // [B][H] recurrent state (coherent)
    float* __restrict__ gates_pre,      // [B][4096] scratch (coherent)
    float* __restrict__ out,
    float* __restrict__ h_final,
    float* __restrict__ c_final,
    u32* __restrict__ ex) {

    const int tid  = threadIdx.x;
    const int lane = tid & 63;
    const int w    = tid >> 6;           // 0..7
    const int mi   = blockIdx.x & 1;     // batch half: rows mi*16..+16
    const int g    = blockIdx.x >> 1;    // 0..31: gate cols [g*128, +128)
    const int ni   = g * 8 + w;          // this wave's 16-col tile (0..255)
    const int lr   = lane & 15;
    const int hi   = lane >> 4;
    const int ko   = hi * 8;
    const int cr   = hi * 4;
    const int gcol = ni * 16 + lr;
    const int brow = mi * 16 + cr;

    u32* ptags = ex + mi * 1024;         // 32 producer tags (one 128B line)
    u32* otags = ex + mi * 1024 + 128;   // 16 owner tags (own line)

    __shared__ __align__(16) char hsm[16 * 2048];   // 16 rows x 1024 bf16, XOR-swizzled
    __shared__ __align__(16) u64 gbuf64[2048];      // owner: gates row [4096] f32
    __shared__ float red[2][8];

    // ---- persist this wave's Wh slice (16 cols x 1024 K) ----
    const bf16* wbase = Wh_b + (size_t)gcol * HID + ko;
    bf16x8 bfrag[32];
#pragma unroll
    for (int kk = 0; kk < 32; ++kk)
        bfrag[kk] = *(const bf16x8*)(wbase + kk * 32);

    const int arow = lr * 2048;
    const int axor = (lr & 7) << 4;

    // owner of batch b = mi*16+g iff g<16; c in registers (elems 2*tid+q)
    const bool owner = (g < 16);
    const int b = mi * 16 + g;
    float creg[2];
    if (owner) {
#pragma unroll
        for (int q = 0; q < 2; ++q) creg[q] = c0[b * HID + 2 * tid + q];
    }

    // gx prefetch for t=0
    const u16* gxp0 = (const u16*)gx + ((size_t)brow * GATES + gcol);
    u16 gxu[4];
#pragma unroll
    for (int r = 0; r < 4; ++r)
        gxu[r] = __builtin_nontemporal_load(gxp0 + (size_t)r * GATES);

    for (int t = 0; t < T_STEPS; ++t) {
        // ---- stage h: wave w polls+stages rows {2w, 2w+1} as they arrive ----
        {
            const int row0 = 2 * w + (lane >> 5);    // half-wave per row
            const int l5 = lane & 31;
            u32 v = ldc_u32(otags + row0);
            while (!__all((int)(v >= (u32)t)))
                v = ldc_u32(otags + row0);
            const u64* hsrc = (const u64*)(h_b + (size_t)(mi * 16 + row0) * HID);
            char* drow = hsm + row0 * 2048;
            const int sx = (row0 & 7) << 4;
#pragma unroll
            for (int k = 0; k < 8; ++k) {
                int j = k * 32 + l5;                 // u64 index within 2KB row
                u64 hv = ldc_u64(hsrc + j);
                *(u64*)(drow + ((j * 8) ^ sx)) = hv;
            }
        }
        __syncthreads();

        // ---- MFMA: 16 batches x 16 gate cols, K=1024 (B resident) ----
        {
            f32x4 acc = {0.f, 0.f, 0.f, 0.f};
#pragma unroll
            for (int kk = 0; kk < 32; ++kk) {
                bf16x8 a = *(const bf16x8*)(hsm + arow + ((kk * 64 + ko * 2) ^ axor));
                acc = __builtin_amdgcn_mfma_f32_16x16x32_bf16(a, bfrag[kk], acc, 0, 0, 0);
            }
            float* gp = gates_pre + (size_t)brow * GATES + gcol;
#pragma unroll
            for (int r = 0; r < 4; ++r) {
                union { u16 u; bf16 h; } cv; cv.u = gxu[r];
                stc_f32(gp + (size_t)r * GATES, acc[r] + __bfloat162float(cv.h));
            }
        }
        // gates release: per-wave drain, block-sync, one tag store
        asm volatile("s_waitcnt vmcnt(0)" ::: "memory");
        __syncthreads();
        if (tid == 0) stc_u32(ptags + g, (u32)(t + 1));

        // ---- owners: pipelined gate gather + LN + cell ----
        if (owner) {
            // wave w: poll producers 4w..4w+3, read their 2KB (256 u64),
            // accumulate sum/sumsq, deposit into gbuf64 (u64 idx = col pair)
            float s = 0.f, s2 = 0.f;
            {
                u32 v = ldc_u32(ptags + 4 * w + hi);   // 16 lanes per tag
                while (!__all((int)(v >= (u32)(t + 1))))
                    v = ldc_u32(ptags + 4 * w + hi);
                const u64* grow = (const u64*)(gates_pre + (size_t)b * GATES);
#pragma unroll
                for (int k = 0; k < 4; ++k) {
                    int idx = w * 256 + k * 64 + lane;
                    union { u64 u; float f[2]; } p; p.u = ldc_u64(grow + idx);
                    gbuf64[idx] = p.u;
                    s  += p.f[0] + p.f[1];
                    s2 += p.f[0] * p.f[0] + p.f[1] * p.f[1];
                }
            }
            // combine: wave reduce -> LDS -> all threads sum 8
#pragma unroll
            for (int off = 32; off > 0; off >>= 1) {
                s  += __shfl_down(s, off, 64);
                s2 += __shfl_down(s2, off, 64);
            }
            if (lane == 0) { red[0][w] = s; red[1][w] = s2; }
            __syncthreads();
            s  = red[0][0] + red[0][1] + red[0][2] + red[0][3]
               + red[0][4] + red[0][5] + red[0][6] + red[0][7];
            s2 = red[1][0] + red[1][1] + red[1][2] + red[1][3]
               + red[1][4] + red[1][5] + red[1][6] + red[1][7];
            const float mu   = s * (1.0f / GATES);
            const float rstd = rsqrtf(s2 * (1.0f / GATES) - mu * mu + 1e-5f);

            // cell: i/f/g/o for cols {2tid, 2tid+1} from gbuf
            float ov[2], cn_[2];
            float cs = 0.f, cs2 = 0.f;
            {
                union { u64 u; float f[2]; } vi, vf, vg, vo;
                vi.u = gbuf64[tid];
                vf.u = gbuf64[512 + tid];
                vg.u = gbuf64[1024 + tid];
                vo.u = gbuf64[1536 + tid];
#pragma unroll
                for (int q = 0; q < 2; ++q) {
                    int j = 2 * tid + q;
                    float iv = sigmf(   (vi.f[q] - mu) * rstd * gn_g[j]           + gn_b[j]);
                    float fv = sigmf(   (vf.f[q] - mu) * rstd * gn_g[HID + j]     + gn_b[HID + j]);
                    float gg = tanhfast((vg.f[q] - mu) * rstd * gn_g[2 * HID + j] + gn_b[2 * HID + j]);
                    ov[q] =             (vo.f[q] - mu) * rstd * gn_g[3 * HID + j] + gn_b[3 * HID + j];
                    float cnew = fv * creg[q] + iv * gg;
                    cn_[q] = cnew;
                    cs += cnew; cs2 += cnew * cnew;
                }
            }
            // c-LN block reduce
#pragma unroll
            for (int off = 32; off > 0; off >>= 1) {
                cs  += __shfl_down(cs, off, 64);
                cs2 += __shfl_down(cs2, off, 64);
            }
            __syncthreads();   // red reuse
            if (lane == 0) { red[0][w] = cs; red[1][w] = cs2; }
            __syncthreads();
            cs  = red[0][0] + red[0][1] + red[0][2] + red[0][3]
                + red[0][4] + red[0][5] + red[0][6] + red[0][7];
            cs2 = red[1][0] + red[1][1] + red[1][2] + red[1][3]
                + red[1][4] + red[1][5] + red[1][6] + red[1][7];
            const float mu2   = cs * (1.0f / HID);
            const float rstd2 = rsqrtf(cs2 * (1.0f / HID) - mu2 * mu2 + 1e-5f);

            // c-LN, h; publish h FIRST, then otag, then deferred out stores
            float hv_[2];
            union { u32 u; unsigned short h2[2]; } hpack;
#pragma unroll
            for (int q = 0; q < 2; ++q) {
                float cn = (cn_[q] - mu2) * rstd2 * cn_g[2 * tid + q] + cn_b[2 * tid + q];
                creg[q] = cn;
                hv_[q] = sigmf(ov[q]) * tanhfast(cn);
                hpack.h2[q] = __bfloat16_as_ushort(__float2bfloat16(hv_[q]));
            }
            stc_u32((u32*)(h_b + (size_t)b * HID + 2 * tid), hpack.u);
            asm volatile("s_waitcnt vmcnt(0)" ::: "memory");
            __syncthreads();
            if (tid == 0) stc_u32(otags + g, (u32)(t + 1));

            // deferred: out (NT) and finals -- off the critical path
            float* orow = out + ((size_t)t * BATCH + b) * HID + 2 * tid;
#pragma unroll
            for (int q = 0; q < 2; ++q)
                __builtin_nontemporal_store(hv_[q], orow + q);
            if (t == T_STEPS - 1) {
#pragma unroll
                for (int q = 0; q < 2; ++q) {
                    h_final[b * HID + 2 * tid + q] = hv_[q];
                    c_final[b * HID + 2 * tid + q] = creg[q];
                }
            }
        }

        // ---- prefetch gx(t+1) (overlaps next stage-poll) ----
        if (t + 1 < T_STEPS) {
            const u16* gxt = gxp0 + (size_t)(t + 1) * (BATCH * GATES);
#pragma unroll
            for (int r = 0; r < 4; ++r)
                gxu[r] = __builtin_nontemporal_load(gxt + (size_t)r * GATES);
        }
        // no bottom barrier: next iteration's per-wave stage-poll syncs on otags
    }
}

// ----------------------------------------------------------- launcher ----
extern "C" void kernel_launch(void* const* d_in, const int* in_sizes, int n_in,
                              void* d_out, int out_size, void* d_ws, size_t ws_size,
                              hipStream_t stream) {
    const float* input = (const float*)d_in[0];
    const float* h0    = (const float*)d_in[1];
    const float* c0    = (const float*)d_in[2];
    const float* Wx    = (const float*)d_in[3];
    const float* Wh    = (const float*)d_in[4];
    const float* gn_g  = (const float*)d_in[5];
    const float* gn_b  = (const float*)d_in[6];
    const float* cn_g  = (const float*)d_in[7];
    const float* cn_b  = (const float*)d_in[8];

    char* ws = (char*)d_ws;
    size_t off = 0;
    auto alloc = [&](size_t bytes) -> char* {
        char* p = ws + off;
        off += (bytes + 255) & ~(size_t)255;
        return p;
    };
    bf16*  input_b   = (bf16*) alloc((size_t)T_STEPS * BATCH * DIM * 2);
    bf16*  Wx_b      = (bf16*) alloc((size_t)GATES * DIM * 2);
    bf16*  Wh_b      = (bf16*) alloc((size_t)GATES * DIM * 2);
    bf16*  gates_x   = (bf16*) alloc((size_t)T_STEPS * BATCH * GATES * 2);
    float* gates_pre = (float*)alloc((size_t)BATCH * GATES * 4);
    bf16*  h_b       = (bf16*) alloc((size_t)BATCH * HID * 2);
    off = (off + 4095) & ~(size_t)4095;
    u32* ex = (u32*)(ws + off);          // 2 halves x 4KB tag state
    off += 8192;

    float* outp    = (float*)d_out;
    float* h_final = outp + (size_t)T_STEPS * BATCH * HID;
    float* c_final = h_final + (size_t)BATCH * HID;

    hipLaunchKernelGGL(prep_kernel, dim3(2048), dim3(256), 0, stream,
                       input, Wx, Wh, h0, input_b, Wx_b, Wh_b, h_b, ex);

    hipLaunchKernelGGL(gemm_input, dim3(4096), dim3(256), 0, stream,
                       input_b, Wx_b, gates_x);

    hipLaunchKernelGGL(scan_kernel, dim3(NBLK), dim3(512), 0, stream,
                       gates_x, Wh_b, c0, gn_g, gn_b, cn_g, cn_b,
                       h_b, gates_pre, outp, h_final, c_final, ex);
}

// Round 9
// 5194.057 us; speedup vs baseline: 2.1924x; 1.0830x over previous
//
#include <hip/hip_runtime.h>
#include <hip/hip_bf16.h>

typedef __hip_bfloat16 bf16;
typedef __attribute__((ext_vector_type(4))) float f32x4;
typedef __attribute__((ext_vector_type(8))) short bf16x8;
typedef unsigned long long u64;
typedef unsigned short u16;
typedef unsigned u32;

#define T_STEPS 512
#define BATCH   32
#define DIM     1024
#define HID     1024
#define GATES   4096
#define NBLK    64    // 2 halves x 32 blocks, 512 threads each

static __device__ __forceinline__ float sigmf(float x) {
    return 1.0f / (1.0f + __expf(-x));
}
// overflow-safe tanh via exp: +/-inf exp -> correct +/-1, no NaN
static __device__ __forceinline__ float tanhfast(float x) {
    return 1.0f - 2.0f / (__expf(2.0f * x) + 1.0f);
}

// coherent (LLC-level) helpers: relaxed agent atomics -> sc-qualified ops,
// no cache-wide fences; L1/L2 stay warm for Wh/gx.
static __device__ __forceinline__ u64 ldc_u64(const u64* p) {
    return __hip_atomic_load((u64*)p, __ATOMIC_RELAXED, __HIP_MEMORY_SCOPE_AGENT);
}
static __device__ __forceinline__ void stc_f32(float* p, float v) {
    __hip_atomic_store(p, v, __ATOMIC_RELAXED, __HIP_MEMORY_SCOPE_AGENT);
}
static __device__ __forceinline__ void stc_u32(u32* p, u32 v) {
    __hip_atomic_store(p, v, __ATOMIC_RELAXED, __HIP_MEMORY_SCOPE_AGENT);
}
static __device__ __forceinline__ u32 ldc_u32(const u32* p) {
    return __hip_atomic_load((u32*)p, __ATOMIC_RELAXED, __HIP_MEMORY_SCOPE_AGENT);
}

// ---------------------------------------------------------------- prep ----
__global__ void prep_kernel(const float* __restrict__ input,
                            const float* __restrict__ Wx,
                            const float* __restrict__ Wh,
                            const float* __restrict__ h0,
                            bf16* __restrict__ input_b,
                            bf16* __restrict__ Wx_b,
                            bf16* __restrict__ Wh_b,
                            bf16* __restrict__ h_b,
                            u32* __restrict__ ex) {
    const size_t NIN = (size_t)T_STEPS * BATCH * DIM;
    const size_t NW  = (size_t)GATES * DIM;
    const size_t NH  = (size_t)BATCH * HID;
    const size_t stride = (size_t)gridDim.x * blockDim.x;
    const size_t t0 = (size_t)blockIdx.x * blockDim.x + threadIdx.x;
    for (size_t i = t0; i < NIN; i += stride) input_b[i] = __float2bfloat16(input[i]);
    for (size_t i = t0; i < NW;  i += stride) Wx_b[i]    = __float2bfloat16(Wx[i]);
    for (size_t i = t0; i < NW;  i += stride) Wh_b[i]    = __float2bfloat16(Wh[i]);
    for (size_t i = t0; i < NH;  i += stride) h_b[i]     = __float2bfloat16(h0[i]);
    if (t0 < 2048) ex[t0] = 0u;   // 2 halves x 4KB tag state (every launch)
}

// ------------------------------------------------- big GEMM: gates_x -----
__global__ __launch_bounds__(256) void gemm_input(const bf16* __restrict__ A,
                                                  const bf16* __restrict__ W,
                                                  bf16* __restrict__ C) {
    const int bn = blockIdx.x & 31;
    const int bm = blockIdx.x >> 5;
    const int lane = threadIdx.x & 63;
    const int w = threadIdx.x >> 6;
    const int wm = (w >> 1) * 64, wn = (w & 1) * 64;
    const int lr = lane & 15;
    const int ko = (lane >> 4) * 8;

    const bf16* Abase = A + (size_t)(bm * 128 + wm + lr) * DIM + ko;
    const bf16* Wbase = W + (size_t)(bn * 128 + wn + lr) * DIM + ko;

    f32x4 acc[4][4] = {};
    for (int k = 0; k < DIM; k += 32) {
        bf16x8 af[4], bw[4];
#pragma unroll
        for (int m = 0; m < 4; ++m)
            af[m] = *(const bf16x8*)(Abase + (size_t)m * 16 * DIM + k);
#pragma unroll
        for (int n = 0; n < 4; ++n)
            bw[n] = *(const bf16x8*)(Wbase + (size_t)n * 16 * DIM + k);
#pragma unroll
        for (int m = 0; m < 4; ++m)
#pragma unroll
            for (int n = 0; n < 4; ++n)
                acc[m][n] = __builtin_amdgcn_mfma_f32_16x16x32_bf16(af[m], bw[n], acc[m][n], 0, 0, 0);
    }
    const int cr = (lane >> 4) * 4;
#pragma unroll
    for (int m = 0; m < 4; ++m)
#pragma unroll
        for (int n = 0; n < 4; ++n)
#pragma unroll
            for (int r = 0; r < 4; ++r) {
                int row = bm * 128 + wm + m * 16 + cr + r;
                int col = bn * 128 + wn + n * 16 + lr;
                C[(size_t)row * GATES + col] = __float2bfloat16(acc[m][n][r]);
            }
}

// -------------------------------------------------- persistent scan ------
// 2 halves (mi) x 32 blocks (g). 8 waves x 512 threads. Wh slices persist
// in VGPR/AGPR. Tags: ONE per 64B line (stride-16 u32), all polls s_sleep
// paced -- polls never contend with the tag stores (r2/r8 lesson).
__global__ __launch_bounds__(512, 2) void scan_kernel(
    const bf16* __restrict__ gx,        // [T][B][4096] bf16
    const bf16* __restrict__ Wh_b,      // [4096][1024] bf16
    const float* __restrict__ c0,
    const float* __restrict__ gn_g, const float* __restrict__ gn_b,
    const float* __restrict__ cn_g, const float* __restrict__ cn_b,
    bf16* __restrict__ h_b,             // [B][H] recurrent state (coherent)
    float* __restrict__ gates_pre,      // [B][4096] scratch (coherent)
    float* __restrict__ out,
    float* __restrict__ h_final,
    float* __restrict__ c_final,
    u32* __restrict__ ex) {

    const int tid  = threadIdx.x;
    const int lane = tid & 63;
    const int w    = tid >> 6;           // 0..7
    const int mi   = blockIdx.x & 1;     // batch half: rows mi*16..+16
    const int g    = blockIdx.x >> 1;    // 0..31: gate cols [g*128, +128)
    const int ni   = g * 8 + w;          // this wave's 16-col tile (0..255)
    const int lr   = lane & 15;
    const int hi   = lane >> 4;
    const int ko   = hi * 8;
    const int cr   = hi * 4;
    const int gcol = ni * 16 + lr;
    const int brow = mi * 16 + cr;

    // per-half tag state: ptags g at +g*16 (64B/line), otags row at +512+row*16
    u32* ptags = ex + mi * 1024;
    u32* otags = ex + mi * 1024 + 512;

    __shared__ __align__(16) char hsm[16 * 2048];   // 16 rows x 1024 bf16, XOR-swizzled
    __shared__ __align__(16) u64 gbuf64[2048];      // owner: gates row [4096] f32
    __shared__ float red[2][8];

    // ---- persist this wave's Wh slice (16 cols x 1024 K) ----
    const bf16* wbase = Wh_b + (size_t)gcol * HID + ko;
    bf16x8 bfrag[32];
#pragma unroll
    for (int kk = 0; kk < 32; ++kk)
        bfrag[kk] = *(const bf16x8*)(wbase + kk * 32);

    const int arow = lr * 2048;
    const int axor = (lr & 7) << 4;

    // owner of batch b = mi*16+g iff g<16; c in registers (elems 2*tid+q)
    const bool owner = (g < 16);
    const int b = mi * 16 + g;
    float creg[2];
    if (owner) {
#pragma unroll
        for (int q = 0; q < 2; ++q) creg[q] = c0[b * HID + 2 * tid + q];
    }

    // gx prefetch for t=0
    const u16* gxp0 = (const u16*)gx + ((size_t)brow * GATES + gcol);
    u16 gxu[4];
#pragma unroll
    for (int r = 0; r < 4; ++r)
        gxu[r] = __builtin_nontemporal_load(gxp0 + (size_t)r * GATES);

    for (int t = 0; t < T_STEPS; ++t) {
        // ---- stage h: half-wave polls+stages its row as it arrives ----
        {
            const int row0 = 2 * w + (lane >> 5);    // half-wave per row
            const int l5 = lane & 31;
            u32 v = ldc_u32(otags + row0 * 16);
            while (!__all((int)(v >= (u32)t))) {
                __builtin_amdgcn_s_sleep(1);
                v = ldc_u32(otags + row0 * 16);
            }
            const u64* hsrc = (const u64*)(h_b + (size_t)(mi * 16 + row0) * HID);
            char* drow = hsm + row0 * 2048;
            const int sx = (row0 & 7) << 4;
#pragma unroll
            for (int k = 0; k < 8; ++k) {
                int j = k * 32 + l5;                 // u64 index within 2KB row
                u64 hv = ldc_u64(hsrc + j);
                *(u64*)(drow + ((j * 8) ^ sx)) = hv;
            }
        }
        __syncthreads();

        // ---- MFMA: 16 batches x 16 gate cols, K=1024 (B resident) ----
        {
            f32x4 acc = {0.f, 0.f, 0.f, 0.f};
#pragma unroll
            for (int kk = 0; kk < 32; ++kk) {
                bf16x8 a = *(const bf16x8*)(hsm + arow + ((kk * 64 + ko * 2) ^ axor));
                acc = __builtin_amdgcn_mfma_f32_16x16x32_bf16(a, bfrag[kk], acc, 0, 0, 0);
            }
            float* gp = gates_pre + (size_t)brow * GATES + gcol;
#pragma unroll
            for (int r = 0; r < 4; ++r) {
                union { u16 u; bf16 h; } cv; cv.u = gxu[r];
                stc_f32(gp + (size_t)r * GATES, acc[r] + __bfloat162float(cv.h));
            }
        }
        // gates release: per-wave drain, block-sync, one tag store
        asm volatile("s_waitcnt vmcnt(0)" ::: "memory");
        __syncthreads();
        if (tid == 0) stc_u32(ptags + g * 16, (u32)(t + 1));

        // ---- owners: pipelined gate gather + LN + cell ----
        if (owner) {
            // wave w: poll producers 4w..4w+3 (each tag its own line; 16
            // lanes broadcast-load one line), read their 2KB, accumulate
            // sum/sumsq, deposit into gbuf64
            float s = 0.f, s2 = 0.f;
            {
                u32 v = ldc_u32(ptags + (4 * w + hi) * 16);
                while (!__all((int)(v >= (u32)(t + 1)))) {
                    __builtin_amdgcn_s_sleep(1);
                    v = ldc_u32(ptags + (4 * w + hi) * 16);
                }
                const u64* grow = (const u64*)(gates_pre + (size_t)b * GATES);
#pragma unroll
                for (int k = 0; k < 4; ++k) {
                    int idx = w * 256 + k * 64 + lane;
                    union { u64 u; float f[2]; } p; p.u = ldc_u64(grow + idx);
                    gbuf64[idx] = p.u;
                    s  += p.f[0] + p.f[1];
                    s2 += p.f[0] * p.f[0] + p.f[1] * p.f[1];
                }
            }
            // combine: wave reduce -> LDS -> all threads sum 8
#pragma unroll
            for (int off = 32; off > 0; off >>= 1) {
                s  += __shfl_down(s, off, 64);
                s2 += __shfl_down(s2, off, 64);
            }
            if (lane == 0) { red[0][w] = s; red[1][w] = s2; }
            __syncthreads();
            s  = red[0][0] + red[0][1] + red[0][2] + red[0][3]
               + red[0][4] + red[0][5] + red[0][6] + red[0][7];
            s2 = red[1][0] + red[1][1] + red[1][2] + red[1][3]
               + red[1][4] + red[1][5] + red[1][6] + red[1][7];
            const float mu   = s * (1.0f / GATES);
            const float rstd = rsqrtf(s2 * (1.0f / GATES) - mu * mu + 1e-5f);

            // cell: i/f/g/o for cols {2tid, 2tid+1} from gbuf
            float ov[2], cn_[2];
            float cs = 0.f, cs2 = 0.f;
            {
                union { u64 u; float f[2]; } vi, vf, vg, vo;
                vi.u = gbuf64[tid];
                vf.u = gbuf64[512 + tid];
                vg.u = gbuf64[1024 + tid];
                vo.u = gbuf64[1536 + tid];
#pragma unroll
                for (int q = 0; q < 2; ++q) {
                    int j = 2 * tid + q;
                    float iv = sigmf(   (vi.f[q] - mu) * rstd * gn_g[j]           + gn_b[j]);
                    float fv = sigmf(   (vf.f[q] - mu) * rstd * gn_g[HID + j]     + gn_b[HID + j]);
                    float gg = tanhfast((vg.f[q] - mu) * rstd * gn_g[2 * HID + j] + gn_b[2 * HID + j]);
                    ov[q] =             (vo.f[q] - mu) * rstd * gn_g[3 * HID + j] + gn_b[3 * HID + j];
                    float cnew = fv * creg[q] + iv * gg;
                    cn_[q] = cnew;
                    cs += cnew; cs2 += cnew * cnew;
                }
            }
            // c-LN block reduce
#pragma unroll
            for (int off = 32; off > 0; off >>= 1) {
                cs  += __shfl_down(cs, off, 64);
                cs2 += __shfl_down(cs2, off, 64);
            }
            __syncthreads();   // red reuse
            if (lane == 0) { red[0][w] = cs; red[1][w] = cs2; }
            __syncthreads();
            cs  = red[0][0] + red[0][1] + red[0][2] + red[0][3]
                + red[0][4] + red[0][5] + red[0][6] + red[0][7];
            cs2 = red[1][0] + red[1][1] + red[1][2] + red[1][3]
                + red[1][4] + red[1][5] + red[1][6] + red[1][7];
            const float mu2   = cs * (1.0f / HID);
            const float rstd2 = rsqrtf(cs2 * (1.0f / HID) - mu2 * mu2 + 1e-5f);

            // c-LN, h; publish h FIRST, then otag, then deferred out stores
            float hv_[2];
            union { u32 u; unsigned short h2[2]; } hpack;
#pragma unroll
            for (int q = 0; q < 2; ++q) {
                float cn = (cn_[q] - mu2) * rstd2 * cn_g[2 * tid + q] + cn_b[2 * tid + q];
                creg[q] = cn;
                hv_[q] = sigmf(ov[q]) * tanhfast(cn);
                hpack.h2[q] = __bfloat16_as_ushort(__float2bfloat16(hv_[q]));
            }
            stc_u32((u32*)(h_b + (size_t)b * HID + 2 * tid), hpack.u);
            asm volatile("s_waitcnt vmcnt(0)" ::: "memory");
            __syncthreads();
            if (tid == 0) stc_u32(otags + g * 16, (u32)(t + 1));

            // deferred: out (NT) and finals -- off the critical path
            float* orow = out + ((size_t)t * BATCH + b) * HID + 2 * tid;
#pragma unroll
            for (int q = 0; q < 2; ++q)
                __builtin_nontemporal_store(hv_[q], orow + q);
            if (t == T_STEPS - 1) {
#pragma unroll
                for (int q = 0; q < 2; ++q) {
                    h_final[b * HID + 2 * tid + q] = hv_[q];
                    c_final[b * HID + 2 * tid + q] = creg[q];
                }
            }
        }

        // ---- prefetch gx(t+1) (overlaps next stage-poll) ----
        if (t + 1 < T_STEPS) {
            const u16* gxt = gxp0 + (size_t)(t + 1) * (BATCH * GATES);
#pragma unroll
            for (int r = 0; r < 4; ++r)
                gxu[r] = __builtin_nontemporal_load(gxt + (size_t)r * GATES);
        }
        // no bottom barrier: next iteration's per-row stage-poll syncs on otags
    }
}

// ----------------------------------------------------------- launcher ----
extern "C" void kernel_launch(void* const* d_in, const int* in_sizes, int n_in,
                              void* d_out, int out_size, void* d_ws, size_t ws_size,
                              hipStream_t stream) {
    const float* input = (const float*)d_in[0];
    const float* h0    = (const float*)d_in[1];
    const float* c0    = (const float*)d_in[2];
    const float* Wx    = (const float*)d_in[3];
    const float* Wh    = (const float*)d_in[4];
    const float* gn_g  = (const float*)d_in[5];
    const float* gn_b  = (const float*)d_in[6];
    const float* cn_g  = (const float*)d_in[7];
    const float* cn_b  = (const float*)d_in[8];

    char* ws = (char*)d_ws;
    size_t off = 0;
    auto alloc = [&](size_t bytes) -> char* {
        char* p = ws + off;
        off += (bytes + 255) & ~(size_t)255;
        return p;
    };
    bf16*  input_b   = (bf16*) alloc((size_t)T_STEPS * BATCH * DIM * 2);
    bf16*  Wx_b      = (bf16*) alloc((size_t)GATES * DIM * 2);
    bf16*  Wh_b      = (bf16*) alloc((size_t)GATES * DIM * 2);
    bf16*  gates_x   = (bf16*) alloc((size_t)T_STEPS * BATCH * GATES * 2);
    float* gates_pre = (float*)alloc((size_t)BATCH * GATES * 4);
    bf16*  h_b       = (bf16*) alloc((size_t)BATCH * HID * 2);
    off = (off + 4095) & ~(size_t)4095;
    u32* ex = (u32*)(ws + off);          // 2 halves x 4KB tag state
    off += 8192;

    float* outp    = (float*)d_out;
    float* h_final = outp + (size_t)T_STEPS * BATCH * HID;
    float* c_final = h_final + (size_t)BATCH * HID;

    hipLaunchKernelGGL(prep_kernel, dim3(2048), dim3(256), 0, stream,
                       input, Wx, Wh, h0, input_b, Wx_b, Wh_b, h_b, ex);

    hipLaunchKernelGGL(gemm_input, dim3(4096), dim3(256), 0, stream,
                       input_b, Wx_b, gates_x);

    hipLaunchKernelGGL(scan_kernel, dim3(NBLK), dim3(512), 0, stream,
                       gates_x, Wh_b, c0, gn_g, gn_b, cn_g, cn_b,
                       h_b, gates_pre, outp, h_final, c_final, ex);
}

// Round 10
// 5145.382 us; speedup vs baseline: 2.2131x; 1.0095x over previous
//
#include <hip/hip_runtime.h>
#include <hip/hip_bf16.h>

typedef __hip_bfloat16 bf16;
typedef __attribute__((ext_vector_type(4))) float f32x4;
typedef __attribute__((ext_vector_type(8))) short bf16x8;
typedef unsigned long long u64;
typedef unsigned short u16;
typedef unsigned u32;

#define T_STEPS 512
#define BATCH   32
#define DIM     1024
#define HID     1024
#define GATES   4096
#define NBLK    64    // 2 halves x 32 blocks, 512 threads each

static __device__ __forceinline__ float sigmf(float x) {
    return 1.0f / (1.0f + __expf(-x));
}
// overflow-safe tanh via exp: +/-inf exp -> correct +/-1, no NaN
static __device__ __forceinline__ float tanhfast(float x) {
    return 1.0f - 2.0f / (__expf(2.0f * x) + 1.0f);
}

// coherent (LLC-level) helpers: relaxed agent atomics -> sc-qualified ops,
// no cache-wide fences; L1/L2 stay warm for Wh/gx.
static __device__ __forceinline__ u64 ldc_u64(const u64* p) {
    return __hip_atomic_load((u64*)p, __ATOMIC_RELAXED, __HIP_MEMORY_SCOPE_AGENT);
}
static __device__ __forceinline__ void stc_u64(u64* p, u64 v) {
    __hip_atomic_store(p, v, __ATOMIC_RELAXED, __HIP_MEMORY_SCOPE_AGENT);
}

// ---------------------------------------------------------------- prep ----
// hx[i] = (tag=0)<<16 | bf16(h0).  gates_u cleared (kills stale tags across
// graph replays).  Runs before scan every launch (stream-ordered).
__global__ void prep_kernel(const float* __restrict__ input,
                            const float* __restrict__ Wx,
                            const float* __restrict__ Wh,
                            const float* __restrict__ h0,
                            bf16* __restrict__ input_b,
                            bf16* __restrict__ Wx_b,
                            bf16* __restrict__ Wh_b,
                            u32* __restrict__ hx,
                            u64* __restrict__ gates_u) {
    const size_t NIN = (size_t)T_STEPS * BATCH * DIM;
    const size_t NW  = (size_t)GATES * DIM;
    const size_t NH  = (size_t)BATCH * HID;
    const size_t NG  = (size_t)BATCH * GATES;
    const size_t stride = (size_t)gridDim.x * blockDim.x;
    const size_t t0 = (size_t)blockIdx.x * blockDim.x + threadIdx.x;
    for (size_t i = t0; i < NIN; i += stride) input_b[i] = __float2bfloat16(input[i]);
    for (size_t i = t0; i < NW;  i += stride) Wx_b[i]    = __float2bfloat16(Wx[i]);
    for (size_t i = t0; i < NW;  i += stride) Wh_b[i]    = __float2bfloat16(Wh[i]);
    for (size_t i = t0; i < NH;  i += stride)
        hx[i] = (u32)__bfloat16_as_ushort(__float2bfloat16(h0[i]));   // tag 0
    for (size_t i = t0; i < NG;  i += stride) gates_u[i] = 0;         // tag 0
}

// ------------------------------------------------- big GEMM: gates_x -----
__global__ __launch_bounds__(256) void gemm_input(const bf16* __restrict__ A,
                                                  const bf16* __restrict__ W,
                                                  bf16* __restrict__ C) {
    const int bn = blockIdx.x & 31;
    const int bm = blockIdx.x >> 5;
    const int lane = threadIdx.x & 63;
    const int w = threadIdx.x >> 6;
    const int wm = (w >> 1) * 64, wn = (w & 1) * 64;
    const int lr = lane & 15;
    const int ko = (lane >> 4) * 8;

    const bf16* Abase = A + (size_t)(bm * 128 + wm + lr) * DIM + ko;
    const bf16* Wbase = W + (size_t)(bn * 128 + wn + lr) * DIM + ko;

    f32x4 acc[4][4] = {};
    for (int k = 0; k < DIM; k += 32) {
        bf16x8 af[4], bw[4];
#pragma unroll
        for (int m = 0; m < 4; ++m)
            af[m] = *(const bf16x8*)(Abase + (size_t)m * 16 * DIM + k);
#pragma unroll
        for (int n = 0; n < 4; ++n)
            bw[n] = *(const bf16x8*)(Wbase + (size_t)n * 16 * DIM + k);
#pragma unroll
        for (int m = 0; m < 4; ++m)
#pragma unroll
            for (int n = 0; n < 4; ++n)
                acc[m][n] = __builtin_amdgcn_mfma_f32_16x16x32_bf16(af[m], bw[n], acc[m][n], 0, 0, 0);
    }
    const int cr = (lane >> 4) * 4;
#pragma unroll
    for (int m = 0; m < 4; ++m)
#pragma unroll
        for (int n = 0; n < 4; ++n)
#pragma unroll
            for (int r = 0; r < 4; ++r) {
                int row = bm * 128 + wm + m * 16 + cr + r;
                int col = bn * 128 + wn + n * 16 + lr;
                C[(size_t)row * GATES + col] = __float2bfloat16(acc[m][n][r]);
            }
}

// -------------------------------------------------- persistent scan ------
// 2 halves (mi) x 32 blocks (g). 8 waves x 512 threads. Wh in VGPRs.
// DATA-AS-FLAG: gates_u[b][col] = (t+1)<<32 | f32bits; hx[b][j] =
// (t+1)<<16 | bf16bits. No drains, no tags, no flag hops. Overwrite
// safety by data dependence (h(t+1) written only after gates(t) consumed,
// which proves all h(t) reads completed; symmetric for gates).
__global__ __launch_bounds__(512, 2) void scan_kernel(
    const bf16* __restrict__ gx,        // [T][B][4096] bf16
    const bf16* __restrict__ Wh_b,      // [4096][1024] bf16
    const float* __restrict__ c0,
    const float* __restrict__ gn_g, const float* __restrict__ gn_b,
    const float* __restrict__ cn_g, const float* __restrict__ cn_b,
    u32* __restrict__ hx,               // [B][HID] tagged h (coherent)
    u64* __restrict__ gates_u,          // [B][4096] tagged gates (coherent)
    float* __restrict__ out,
    float* __restrict__ h_final,
    float* __restrict__ c_final) {

    const int tid  = threadIdx.x;
    const int lane = tid & 63;
    const int w    = tid >> 6;           // 0..7
    const int mi   = blockIdx.x & 1;     // batch half: rows mi*16..+16
    const int g    = blockIdx.x >> 1;    // 0..31: gate cols [g*128, +128)
    const int ni   = g * 8 + w;          // this wave's 16-col tile (0..255)
    const int lr   = lane & 15;
    const int hi   = lane >> 4;
    const int ko   = hi * 8;
    const int cr   = hi * 4;
    const int gcol = ni * 16 + lr;
    const int brow = mi * 16 + cr;

    __shared__ __align__(16) char hsm[16 * 2048];   // 16 rows x 1024 bf16, XOR-swizzled
    __shared__ float red[2][8];

    // ---- persist this wave's Wh slice (16 cols x 1024 K) ----
    const bf16* wbase = Wh_b + (size_t)gcol * HID + ko;
    bf16x8 bfrag[32];
#pragma unroll
    for (int kk = 0; kk < 32; ++kk)
        bfrag[kk] = *(const bf16x8*)(wbase + kk * 32);

    const int arow = lr * 2048;
    const int axor = (lr & 7) << 4;

    // owner of batch b = mi*16+g iff g<16; c in registers (elems 2*tid+q)
    const bool owner = (g < 16);
    const int b = mi * 16 + g;
    float creg[2];
    if (owner) {
#pragma unroll
        for (int q = 0; q < 2; ++q) creg[q] = c0[b * HID + 2 * tid + q];
    }

    // gx prefetch for t=0
    const u16* gxp0 = (const u16*)gx + ((size_t)brow * GATES + gcol);
    u16 gxu[4];
#pragma unroll
    for (int r = 0; r < 4; ++r)
        gxu[r] = __builtin_nontemporal_load(gxp0 + (size_t)r * GATES);

    for (int t = 0; t < T_STEPS; ++t) {
        // ---- stage h: half-wave polls+stages its row (tag == t) ----
        {
            const int row0 = 2 * w + (lane >> 5);
            const int l5 = lane & 31;
            const u64* hsrc = (const u64*)(hx + (size_t)(mi * 16 + row0) * HID);
            char* drow = hsm + row0 * 2048;
            const int sx = (row0 & 7) << 4;
            const u32 want = (u32)t;
            u64 vv[16];
#pragma unroll
            for (int k = 0; k < 16; ++k)
                vv[k] = ldc_u64(hsrc + k * 32 + l5);      // 16 loads in flight
            for (;;) {
                bool ok = true;
#pragma unroll
                for (int k = 0; k < 16; ++k) {
                    if ((((u32)(vv[k] >> 16) & 0xFFFFu) != want) ||
                        ((u32)(vv[k] >> 48) != want)) {
                        ok = false;
                        vv[k] = ldc_u64(hsrc + k * 32 + l5);
                    }
                }
                if (ok) break;
                __builtin_amdgcn_s_sleep(0);
            }
#pragma unroll
            for (int k = 0; k < 16; ++k) {
                int j = k * 32 + l5;                      // col pair {2j,2j+1}
                u32 packed = (u32)(vv[k] & 0xFFFFu) |
                             (((u32)(vv[k] >> 32) & 0xFFFFu) << 16);
                *(u32*)(drow + ((4 * j) ^ sx)) = packed;
            }
        }
        __syncthreads();

        // ---- MFMA: 16 batches x 16 gate cols, K=1024 (B resident);
        //      publish tagged gates (self-flagging, no drain) ----
        {
            f32x4 acc = {0.f, 0.f, 0.f, 0.f};
#pragma unroll
            for (int kk = 0; kk < 32; ++kk) {
                bf16x8 a = *(const bf16x8*)(hsm + arow + ((kk * 64 + ko * 2) ^ axor));
                acc = __builtin_amdgcn_mfma_f32_16x16x32_bf16(a, bfrag[kk], acc, 0, 0, 0);
            }
            u64* gp = gates_u + (size_t)brow * GATES + gcol;
            const u64 tagup = (u64)(u32)(t + 1) << 32;
#pragma unroll
            for (int r = 0; r < 4; ++r) {
                union { u16 u; bf16 h; } cv; cv.u = gxu[r];
                float val = acc[r] + __bfloat162float(cv.h);
                stc_u64(gp + (size_t)r * GATES, tagup | (u64)__float_as_uint(val));
            }
        }
        __syncthreads();   // protect hsm for next iteration's staging

        // ---- owners: poll own tagged gates direct-to-register, LN + cell ----
        if (owner) {
            const u64* grow = gates_u + (size_t)b * GATES;
            const u32 want = (u32)(t + 1);
            u64 vg[4][2];
#pragma unroll
            for (int q = 0; q < 4; ++q)
#pragma unroll
                for (int e = 0; e < 2; ++e)
                    vg[q][e] = ldc_u64(grow + q * 1024 + 2 * tid + e);
            for (;;) {
                bool ok = true;
#pragma unroll
                for (int q = 0; q < 4; ++q)
#pragma unroll
                    for (int e = 0; e < 2; ++e)
                        if ((u32)(vg[q][e] >> 32) != want) {
                            ok = false;
                            vg[q][e] = ldc_u64(grow + q * 1024 + 2 * tid + e);
                        }
                if (ok) break;
                __builtin_amdgcn_s_sleep(0);
            }
            float gv[4][2];
            float s = 0.f, s2 = 0.f;
#pragma unroll
            for (int q = 0; q < 4; ++q)
#pragma unroll
                for (int e = 0; e < 2; ++e) {
                    float x = __uint_as_float((u32)vg[q][e]);
                    gv[q][e] = x;
                    s += x; s2 += x * x;
                }
            // block reduce over 8 waves
#pragma unroll
            for (int off = 32; off > 0; off >>= 1) {
                s  += __shfl_down(s, off, 64);
                s2 += __shfl_down(s2, off, 64);
            }
            if (lane == 0) { red[0][w] = s; red[1][w] = s2; }
            __syncthreads();
            s  = red[0][0] + red[0][1] + red[0][2] + red[0][3]
               + red[0][4] + red[0][5] + red[0][6] + red[0][7];
            s2 = red[1][0] + red[1][1] + red[1][2] + red[1][3]
               + red[1][4] + red[1][5] + red[1][6] + red[1][7];
            const float mu   = s * (1.0f / GATES);
            const float rstd = rsqrtf(s2 * (1.0f / GATES) - mu * mu + 1e-5f);

            float ov[2], cn_[2];
            float cs = 0.f, cs2 = 0.f;
#pragma unroll
            for (int q = 0; q < 2; ++q) {
                int j = 2 * tid + q;
                float iv = sigmf(   (gv[0][q] - mu) * rstd * gn_g[j]           + gn_b[j]);
                float fv = sigmf(   (gv[1][q] - mu) * rstd * gn_g[HID + j]     + gn_b[HID + j]);
                float gg = tanhfast((gv[2][q] - mu) * rstd * gn_g[2 * HID + j] + gn_b[2 * HID + j]);
                ov[q] =             (gv[3][q] - mu) * rstd * gn_g[3 * HID + j] + gn_b[3 * HID + j];
                float cnew = fv * creg[q] + iv * gg;
                cn_[q] = cnew;
                cs += cnew; cs2 += cnew * cnew;
            }
#pragma unroll
            for (int off = 32; off > 0; off >>= 1) {
                cs  += __shfl_down(cs, off, 64);
                cs2 += __shfl_down(cs2, off, 64);
            }
            __syncthreads();   // red reuse
            if (lane == 0) { red[0][w] = cs; red[1][w] = cs2; }
            __syncthreads();
            cs  = red[0][0] + red[0][1] + red[0][2] + red[0][3]
                + red[0][4] + red[0][5] + red[0][6] + red[0][7];
            cs2 = red[1][0] + red[1][1] + red[1][2] + red[1][3]
                + red[1][4] + red[1][5] + red[1][6] + red[1][7];
            const float mu2   = cs * (1.0f / HID);
            const float rstd2 = rsqrtf(cs2 * (1.0f / HID) - mu2 * mu2 + 1e-5f);

            // c-LN, h; publish tagged h immediately (self-flagging)
            float hv_[2];
            u32 he[2];
#pragma unroll
            for (int q = 0; q < 2; ++q) {
                float cn = (cn_[q] - mu2) * rstd2 * cn_g[2 * tid + q] + cn_b[2 * tid + q];
                creg[q] = cn;
                hv_[q] = sigmf(ov[q]) * tanhfast(cn);
                he[q] = ((u32)(t + 1) << 16) |
                        (u32)__bfloat16_as_ushort(__float2bfloat16(hv_[q]));
            }
            stc_u64((u64*)(hx + (size_t)b * HID + 2 * tid),
                    (u64)he[0] | ((u64)he[1] << 32));

            // deferred: out (NT) and finals -- off the critical path
            float* orow = out + ((size_t)t * BATCH + b) * HID + 2 * tid;
#pragma unroll
            for (int q = 0; q < 2; ++q)
                __builtin_nontemporal_store(hv_[q], orow + q);
            if (t == T_STEPS - 1) {
#pragma unroll
                for (int q = 0; q < 2; ++q) {
                    h_final[b * HID + 2 * tid + q] = hv_[q];
                    c_final[b * HID + 2 * tid + q] = creg[q];
                }
            }
        }

        // ---- prefetch gx(t+1) (overlaps next stage-poll) ----
        if (t + 1 < T_STEPS) {
            const u16* gxt = gxp0 + (size_t)(t + 1) * (BATCH * GATES);
#pragma unroll
            for (int r = 0; r < 4; ++r)
                gxu[r] = __builtin_nontemporal_load(gxt + (size_t)r * GATES);
        }
        // no bottom barrier: next stage-poll self-syncs on h tags
    }
}

// ----------------------------------------------------------- launcher ----
extern "C" void kernel_launch(void* const* d_in, const int* in_sizes, int n_in,
                              void* d_out, int out_size, void* d_ws, size_t ws_size,
                              hipStream_t stream) {
    const float* input = (const float*)d_in[0];
    const float* h0    = (const float*)d_in[1];
    const float* c0    = (const float*)d_in[2];
    const float* Wx    = (const float*)d_in[3];
    const float* Wh    = (const float*)d_in[4];
    const float* gn_g  = (const float*)d_in[5];
    const float* gn_b  = (const float*)d_in[6];
    const float* cn_g  = (const float*)d_in[7];
    const float* cn_b  = (const float*)d_in[8];

    char* ws = (char*)d_ws;
    size_t off = 0;
    auto alloc = [&](size_t bytes) -> char* {
        char* p = ws + off;
        off += (bytes + 255) & ~(size_t)255;
        return p;
    };
    bf16* input_b = (bf16*)alloc((size_t)T_STEPS * BATCH * DIM * 2);
    bf16* Wx_b    = (bf16*)alloc((size_t)GATES * DIM * 2);
    bf16* Wh_b    = (bf16*)alloc((size_t)GATES * DIM * 2);
    bf16* gates_x = (bf16*)alloc((size_t)T_STEPS * BATCH * GATES * 2);
    u64*  gates_u = (u64*) alloc((size_t)BATCH * GATES * 8);   // tagged gates
    u32*  hx      = (u32*) alloc((size_t)BATCH * HID * 4);     // tagged h

    float* outp    = (float*)d_out;
    float* h_final = outp + (size_t)T_STEPS * BATCH * HID;
    float* c_final = h_final + (size_t)BATCH * HID;

    hipLaunchKernelGGL(prep_kernel, dim3(2048), dim3(256), 0, stream,
                       input, Wx, Wh, h0, input_b, Wx_b, Wh_b, hx, gates_u);

    hipLaunchKernelGGL(gemm_input, dim3(4096), dim3(256), 0, stream,
                       input_b, Wx_b, gates_x);

    hipLaunchKernelGGL(scan_kernel, dim3(NBLK), dim3(512), 0, stream,
                       gates_x, Wh_b, c0, gn_g, gn_b, cn_g, cn_b,
                       hx, gates_u, outp, h_final, c_final);
}

// Round 11
// 4119.827 us; speedup vs baseline: 2.7640x; 1.2489x over previous
//
#include <hip/hip_runtime.h>
#include <hip/hip_bf16.h>

typedef __hip_bfloat16 bf16;
typedef __attribute__((ext_vector_type(4))) float f32x4;
typedef __attribute__((ext_vector_type(8))) short bf16x8;
typedef unsigned long long u64;
typedef unsigned short u16;
typedef unsigned u32;

#define T_STEPS 512
#define BATCH   32
#define DIM     1024
#define HID     1024
#define GATES   4096
#define NPROD   64    // producer blocks: 2 halves x 32, 512 threads
#define NOWN    32    // owner blocks: 1 per batch, 512 threads
#define NBLK    (NPROD + NOWN)

static __device__ __forceinline__ float sigmf(float x) {
    return 1.0f / (1.0f + __expf(-x));
}
// overflow-safe tanh via exp: +/-inf exp -> correct +/-1, no NaN
static __device__ __forceinline__ float tanhfast(float x) {
    return 1.0f - 2.0f / (__expf(2.0f * x) + 1.0f);
}

// coherent (LLC-level) helpers: relaxed agent atomics -> sc-qualified ops,
// no cache-wide fences; L1/L2 stay warm for Wh/gx.
static __device__ __forceinline__ u64 ldc_u64(const u64* p) {
    return __hip_atomic_load((u64*)p, __ATOMIC_RELAXED, __HIP_MEMORY_SCOPE_AGENT);
}
static __device__ __forceinline__ void stc_u64(u64* p, u64 v) {
    __hip_atomic_store(p, v, __ATOMIC_RELAXED, __HIP_MEMORY_SCOPE_AGENT);
}

// ---------------------------------------------------------------- prep ----
// hx[i] = (tag=0)<<16 | bf16(h0).  gates_u cleared (kills stale tags across
// graph replays).  Runs before scan every launch (stream-ordered).
__global__ void prep_kernel(const float* __restrict__ input,
                            const float* __restrict__ Wx,
                            const float* __restrict__ Wh,
                            const float* __restrict__ h0,
                            bf16* __restrict__ input_b,
                            bf16* __restrict__ Wx_b,
                            bf16* __restrict__ Wh_b,
                            u32* __restrict__ hx,
                            u64* __restrict__ gates_u) {
    const size_t NIN = (size_t)T_STEPS * BATCH * DIM;
    const size_t NW  = (size_t)GATES * DIM;
    const size_t NH  = (size_t)BATCH * HID;
    const size_t NG  = (size_t)BATCH * GATES;
    const size_t stride = (size_t)gridDim.x * blockDim.x;
    const size_t t0 = (size_t)blockIdx.x * blockDim.x + threadIdx.x;
    for (size_t i = t0; i < NIN; i += stride) input_b[i] = __float2bfloat16(input[i]);
    for (size_t i = t0; i < NW;  i += stride) Wx_b[i]    = __float2bfloat16(Wx[i]);
    for (size_t i = t0; i < NW;  i += stride) Wh_b[i]    = __float2bfloat16(Wh[i]);
    for (size_t i = t0; i < NH;  i += stride)
        hx[i] = (u32)__bfloat16_as_ushort(__float2bfloat16(h0[i]));   // tag 0
    for (size_t i = t0; i < NG;  i += stride) gates_u[i] = 0;         // tag 0
}

// ------------------------------------------------- big GEMM: gates_x -----
__global__ __launch_bounds__(256) void gemm_input(const bf16* __restrict__ A,
                                                  const bf16* __restrict__ W,
                                                  bf16* __restrict__ C) {
    const int bn = blockIdx.x & 31;
    const int bm = blockIdx.x >> 5;
    const int lane = threadIdx.x & 63;
    const int w = threadIdx.x >> 6;
    const int wm = (w >> 1) * 64, wn = (w & 1) * 64;
    const int lr = lane & 15;
    const int ko = (lane >> 4) * 8;

    const bf16* Abase = A + (size_t)(bm * 128 + wm + lr) * DIM + ko;
    const bf16* Wbase = W + (size_t)(bn * 128 + wn + lr) * DIM + ko;

    f32x4 acc[4][4] = {};
    for (int k = 0; k < DIM; k += 32) {
        bf16x8 af[4], bw[4];
#pragma unroll
        for (int m = 0; m < 4; ++m)
            af[m] = *(const bf16x8*)(Abase + (size_t)m * 16 * DIM + k);
#pragma unroll
        for (int n = 0; n < 4; ++n)
            bw[n] = *(const bf16x8*)(Wbase + (size_t)n * 16 * DIM + k);
#pragma unroll
        for (int m = 0; m < 4; ++m)
#pragma unroll
            for (int n = 0; n < 4; ++n)
                acc[m][n] = __builtin_amdgcn_mfma_f32_16x16x32_bf16(af[m], bw[n], acc[m][n], 0, 0, 0);
    }
    const int cr = (lane >> 4) * 4;
#pragma unroll
    for (int m = 0; m < 4; ++m)
#pragma unroll
        for (int n = 0; n < 4; ++n)
#pragma unroll
            for (int r = 0; r < 4; ++r) {
                int row = bm * 128 + wm + m * 16 + cr + r;
                int col = bn * 128 + wn + n * 16 + lr;
                C[(size_t)row * GATES + col] = __float2bfloat16(acc[m][n][r]);
            }
}

// -------------------------------------------------- persistent scan ------
// Heterogeneous 96-block grid, pure dataflow (data-as-flag, no flags/drains):
//   blocks 0..63  = producers: 2 halves x 32 blocks, Wh in VGPRs. Loop:
//     poll tagged h rows -> stage LDS -> sync -> MFMA -> store tagged gates.
//   blocks 64..95 = owners: block 64+b owns batch b. Loop: poll 8 tagged
//     gate words/thread -> LN reduce -> cell -> c-LN reduce -> publish
//     tagged h -> deferred NT out.
// Producer/owner stages overlap across CUs (each parks on its next poll
// while the other stage computes). Overwrite safety purely by dataflow:
// h(t+1) published only after ALL gates(t) consumed, which proves every
// producer's MFMA(t) (and its hsm reads / h(t) loads) completed; symmetric
// for gates overwrite. Tags monotone; prep reinitializes per launch.
__global__ __launch_bounds__(512, 2) void scan_kernel(
    const bf16* __restrict__ gx,        // [T][B][4096] bf16
    const bf16* __restrict__ Wh_b,      // [4096][1024] bf16
    const float* __restrict__ c0,
    const float* __restrict__ gn_g, const float* __restrict__ gn_b,
    const float* __restrict__ cn_g, const float* __restrict__ cn_b,
    u32* __restrict__ hx,               // [B][HID] tagged h (coherent)
    u64* __restrict__ gates_u,          // [B][4096] tagged gates (coherent)
    float* __restrict__ out,
    float* __restrict__ h_final,
    float* __restrict__ c_final) {

    const int tid  = threadIdx.x;
    const int lane = tid & 63;
    const int w    = tid >> 6;           // 0..7

    if (blockIdx.x < NPROD) {
        // ======================= PRODUCER BLOCK =======================
        const int mi   = blockIdx.x & 1;     // batch half: rows mi*16..+16
        const int g    = blockIdx.x >> 1;    // 0..31: gate cols [g*128, +128)
        const int ni   = g * 8 + w;          // this wave's 16-col tile
        const int lr   = lane & 15;
        const int hi   = lane >> 4;
        const int ko   = hi * 8;
        const int cr   = hi * 4;
        const int gcol = ni * 16 + lr;
        const int brow = mi * 16 + cr;

        __shared__ __align__(16) char hsm[16 * 2048];  // 16 x 1024 bf16, swizzled

        // persist this wave's Wh slice (16 cols x 1024 K) in VGPRs
        const bf16* wbase = Wh_b + (size_t)gcol * HID + ko;
        bf16x8 bfrag[32];
#pragma unroll
        for (int kk = 0; kk < 32; ++kk)
            bfrag[kk] = *(const bf16x8*)(wbase + kk * 32);

        const int arow = lr * 2048;
        const int axor = (lr & 7) << 4;

        // gx prefetch for t=0
        const u16* gxp0 = (const u16*)gx + ((size_t)brow * GATES + gcol);
        u16 gxu[4];
#pragma unroll
        for (int r = 0; r < 4; ++r)
            gxu[r] = __builtin_nontemporal_load(gxp0 + (size_t)r * GATES);

        for (int t = 0; t < T_STEPS; ++t) {
            // ---- stage h: half-wave polls+stages its row (tag == t) ----
            {
                const int row0 = 2 * w + (lane >> 5);
                const int l5 = lane & 31;
                const u64* hsrc = (const u64*)(hx + (size_t)(mi * 16 + row0) * HID);
                char* drow = hsm + row0 * 2048;
                const int sx = (row0 & 7) << 4;
                const u32 want = (u32)t;
                u64 vv[16];
#pragma unroll
                for (int k = 0; k < 16; ++k)
                    vv[k] = ldc_u64(hsrc + k * 32 + l5);      // 16 loads in flight
                for (;;) {
                    bool ok = true;
#pragma unroll
                    for (int k = 0; k < 16; ++k) {
                        if ((((u32)(vv[k] >> 16) & 0xFFFFu) != want) ||
                            ((u32)(vv[k] >> 48) != want)) {
                            ok = false;
                            vv[k] = ldc_u64(hsrc + k * 32 + l5);
                        }
                    }
                    if (ok) break;
                    __builtin_amdgcn_s_sleep(1);
                }
#pragma unroll
                for (int k = 0; k < 16; ++k) {
                    int j = k * 32 + l5;                      // col pair {2j,2j+1}
                    u32 packed = (u32)(vv[k] & 0xFFFFu) |
                                 (((u32)(vv[k] >> 32) & 0xFFFFu) << 16);
                    *(u32*)(drow + ((4 * j) ^ sx)) = packed;
                }
            }
            __syncthreads();   // the ONLY barrier per step

            // ---- MFMA + tagged gates publish (self-flagging) ----
            {
                f32x4 acc = {0.f, 0.f, 0.f, 0.f};
#pragma unroll
                for (int kk = 0; kk < 32; ++kk) {
                    bf16x8 a = *(const bf16x8*)(hsm + arow + ((kk * 64 + ko * 2) ^ axor));
                    acc = __builtin_amdgcn_mfma_f32_16x16x32_bf16(a, bfrag[kk], acc, 0, 0, 0);
                }
                u64* gp = gates_u + (size_t)brow * GATES + gcol;
                const u64 tagup = (u64)(u32)(t + 1) << 32;
#pragma unroll
                for (int r = 0; r < 4; ++r) {
                    union { u16 u; bf16 h; } cv; cv.u = gxu[r];
                    float val = acc[r] + __bfloat162float(cv.h);
                    stc_u64(gp + (size_t)r * GATES, tagup | (u64)__float_as_uint(val));
                }
            }

            // ---- prefetch gx(t+1) (overlaps next h-poll) ----
            if (t + 1 < T_STEPS) {
                const u16* gxt = gxp0 + (size_t)(t + 1) * (BATCH * GATES);
#pragma unroll
                for (int r = 0; r < 4; ++r)
                    gxu[r] = __builtin_nontemporal_load(gxt + (size_t)r * GATES);
            }
            // no end barrier: dataflow (h(t+1) tags) subsumes it
        }
        return;
    }

    // ========================== OWNER BLOCK ==========================
    const int b = blockIdx.x - NPROD;     // batch 0..31
    __shared__ float red[2][8];

    float creg[2];
#pragma unroll
    for (int q = 0; q < 2; ++q) creg[q] = c0[b * HID + 2 * tid + q];

    for (int t = 0; t < T_STEPS; ++t) {
        // ---- poll own tagged gates direct-to-register ----
        const u64* grow = gates_u + (size_t)b * GATES;
        const u32 want = (u32)(t + 1);
        u64 vg[4][2];
#pragma unroll
        for (int q = 0; q < 4; ++q)
#pragma unroll
            for (int e = 0; e < 2; ++e)
                vg[q][e] = ldc_u64(grow + q * 1024 + 2 * tid + e);
        for (;;) {
            bool ok = true;
#pragma unroll
            for (int q = 0; q < 4; ++q)
#pragma unroll
                for (int e = 0; e < 2; ++e)
                    if ((u32)(vg[q][e] >> 32) != want) {
                        ok = false;
                        vg[q][e] = ldc_u64(grow + q * 1024 + 2 * tid + e);
                    }
            if (ok) break;
            __builtin_amdgcn_s_sleep(1);
        }
        float gv[4][2];
        float s = 0.f, s2 = 0.f;
#pragma unroll
        for (int q = 0; q < 4; ++q)
#pragma unroll
            for (int e = 0; e < 2; ++e) {
                float x = __uint_as_float((u32)vg[q][e]);
                gv[q][e] = x;
                s += x; s2 += x * x;
            }
        // block reduce over 8 waves
#pragma unroll
        for (int off = 32; off > 0; off >>= 1) {
            s  += __shfl_down(s, off, 64);
            s2 += __shfl_down(s2, off, 64);
        }
        if (lane == 0) { red[0][w] = s; red[1][w] = s2; }
        __syncthreads();
        s  = red[0][0] + red[0][1] + red[0][2] + red[0][3]
           + red[0][4] + red[0][5] + red[0][6] + red[0][7];
        s2 = red[1][0] + red[1][1] + red[1][2] + red[1][3]
           + red[1][4] + red[1][5] + red[1][6] + red[1][7];
        const float mu   = s * (1.0f / GATES);
        const float rstd = rsqrtf(s2 * (1.0f / GATES) - mu * mu + 1e-5f);

        float ov[2], cn_[2];
        float cs = 0.f, cs2 = 0.f;
#pragma unroll
        for (int q = 0; q < 2; ++q) {
            int j = 2 * tid + q;
            float iv = sigmf(   (gv[0][q] - mu) * rstd * gn_g[j]           + gn_b[j]);
            float fv = sigmf(   (gv[1][q] - mu) * rstd * gn_g[HID + j]     + gn_b[HID + j]);
            float gg = tanhfast((gv[2][q] - mu) * rstd * gn_g[2 * HID + j] + gn_b[2 * HID + j]);
            ov[q] =             (gv[3][q] - mu) * rstd * gn_g[3 * HID + j] + gn_b[3 * HID + j];
            float cnew = fv * creg[q] + iv * gg;
            cn_[q] = cnew;
            cs += cnew; cs2 += cnew * cnew;
        }
#pragma unroll
        for (int off = 32; off > 0; off >>= 1) {
            cs  += __shfl_down(cs, off, 64);
            cs2 += __shfl_down(cs2, off, 64);
        }
        __syncthreads();   // red reuse
        if (lane == 0) { red[0][w] = cs; red[1][w] = cs2; }
        __syncthreads();
        cs  = red[0][0] + red[0][1] + red[0][2] + red[0][3]
            + red[0][4] + red[0][5] + red[0][6] + red[0][7];
        cs2 = red[1][0] + red[1][1] + red[1][2] + red[1][3]
            + red[1][4] + red[1][5] + red[1][6] + red[1][7];
        const float mu2   = cs * (1.0f / HID);
        const float rstd2 = rsqrtf(cs2 * (1.0f / HID) - mu2 * mu2 + 1e-5f);

        // c-LN, h; publish tagged h immediately (self-flagging)
        float hv_[2];
        u32 he[2];
#pragma unroll
        for (int q = 0; q < 2; ++q) {
            float cn = (cn_[q] - mu2) * rstd2 * cn_g[2 * tid + q] + cn_b[2 * tid + q];
            creg[q] = cn;
            hv_[q] = sigmf(ov[q]) * tanhfast(cn);
            he[q] = ((u32)(t + 1) << 16) |
                    (u32)__bfloat16_as_ushort(__float2bfloat16(hv_[q]));
        }
        stc_u64((u64*)(hx + (size_t)b * HID + 2 * tid),
                (u64)he[0] | ((u64)he[1] << 32));

        // deferred: out (NT) and finals -- off the critical path
        float* orow = out + ((size_t)t * BATCH + b) * HID + 2 * tid;
#pragma unroll
        for (int q = 0; q < 2; ++q)
            __builtin_nontemporal_store(hv_[q], orow + q);
        if (t == T_STEPS - 1) {
#pragma unroll
            for (int q = 0; q < 2; ++q) {
                h_final[b * HID + 2 * tid + q] = hv_[q];
                c_final[b * HID + 2 * tid + q] = creg[q];
            }
        }
    }
}

// ----------------------------------------------------------- launcher ----
extern "C" void kernel_launch(void* const* d_in, const int* in_sizes, int n_in,
                              void* d_out, int out_size, void* d_ws, size_t ws_size,
                              hipStream_t stream) {
    const float* input = (const float*)d_in[0];
    const float* h0    = (const float*)d_in[1];
    const float* c0    = (const float*)d_in[2];
    const float* Wx    = (const float*)d_in[3];
    const float* Wh    = (const float*)d_in[4];
    const float* gn_g  = (const float*)d_in[5];
    const float* gn_b  = (const float*)d_in[6];
    const float* cn_g  = (const float*)d_in[7];
    const float* cn_b  = (const float*)d_in[8];

    char* ws = (char*)d_ws;
    size_t off = 0;
    auto alloc = [&](size_t bytes) -> char* {
        char* p = ws + off;
        off += (bytes + 255) & ~(size_t)255;
        return p;
    };
    bf16* input_b = (bf16*)alloc((size_t)T_STEPS * BATCH * DIM * 2);
    bf16* Wx_b    = (bf16*)alloc((size_t)GATES * DIM * 2);
    bf16* Wh_b    = (bf16*)alloc((size_t)GATES * DIM * 2);
    bf16* gates_x = (bf16*)alloc((size_t)T_STEPS * BATCH * GATES * 2);
    u64*  gates_u = (u64*) alloc((size_t)BATCH * GATES * 8);   // tagged gates
    u32*  hx      = (u32*) alloc((size_t)BATCH * HID * 4);     // tagged h

    float* outp    = (float*)d_out;
    float* h_final = outp + (size_t)T_STEPS * BATCH * HID;
    float* c_final = h_final + (size_t)BATCH * HID;

    hipLaunchKernelGGL(prep_kernel, dim3(2048), dim3(256), 0, stream,
                       input, Wx, Wh, h0, input_b, Wx_b, Wh_b, hx, gates_u);

    hipLaunchKernelGGL(gemm_input, dim3(4096), dim3(256), 0, stream,
                       input_b, Wx_b, gates_x);

    hipLaunchKernelGGL(scan_kernel, dim3(NBLK), dim3(512), 0, stream,
                       gates_x, Wh_b, c0, gn_g, gn_b, cn_g, cn_b,
                       hx, gates_u, outp, h_final, c_final);
}